// Round 10
// baseline (731.850 us; speedup 1.0000x reference)
//
#include <hip/hip_runtime.h>
#include <hip/hip_bf16.h>

typedef unsigned short u16;
typedef unsigned long long ull;
typedef __attribute__((ext_vector_type(8))) short bf16x8;
typedef __attribute__((ext_vector_type(4))) float f32x4;
typedef __attribute__((ext_vector_type(4))) int i32x4;

#define NSLICE 500   // 250 vocab tiles * 2 wave-columns

__device__ __forceinline__ u16 f2bf(float x){
  unsigned b = __float_as_uint(x);
  return (u16)((b + 0x7FFFu + ((b>>16)&1u)) >> 16);
}
__device__ __forceinline__ float sigm(float x){ return 1.f/(1.f+__expf(-x)); }

__device__ __forceinline__ void gload_lds16(const void* g, void* l){
  __builtin_amdgcn_global_load_lds(
      (const __attribute__((address_space(1))) unsigned int*)g,
      (__attribute__((address_space(3))) unsigned int*)l, 16, 0, 0);
}
// XOR swizzle within a 128B (64 bf16) row: spreads 8 rows over 8 bank slots.
#define SWZ(row, kb) ((kb) ^ (((row)&7)<<4))

// Coherent (LLC) 16B load with literal offset, forced issue order.
template<int OFF>
__device__ __forceinline__ i32x4 gload16_coh(const char* p){
  i32x4 d;
  asm volatile("global_load_dwordx4 %0, %1, off offset:%2 sc0 sc1"
               : "=v"(d) : "v"(p), "n"(OFF) : "memory");
  return d;
}

// ---- fused prep: Wout/Wih/Whh transpose->bf16, emb gather->bf16, zero state.
__device__ __forceinline__ void transpose_tile(
    const float* __restrict__ in, u16* __restrict__ out, int N, int K,
    int nb, int kb, float (*tile)[65])
{
  const int t = threadIdx.x;
#pragma unroll
  for (int i=0;i<4;++i){
    int idx = i*256 + t;          // 1024 float4 chunks
    int k = idx>>4, n4 = idx&15;
    const float4 v = *(const float4*)&in[(size_t)(kb+k)*N + nb + n4*4];
    tile[k][n4*4+0]=v.x; tile[k][n4*4+1]=v.y; tile[k][n4*4+2]=v.z; tile[k][n4*4+3]=v.w;
  }
  __syncthreads();
#pragma unroll
  for (int i=0;i<2;++i){
    int idx = i*256 + t;          // 512 8-elem bf16 chunks
    int n = idx>>3, k8 = idx&7;
    u16 tmp[8];
#pragma unroll
    for (int jj=0;jj<8;++jj) tmp[jj] = f2bf(tile[k8*8+jj][n]);
    *(ulonglong2*)&out[(size_t)(nb+n)*K + kb + k8*8] = *(ulonglong2*)tmp;
  }
}

__global__ __launch_bounds__(256) void prep_kernel(
    const float* __restrict__ Wout, const float* __restrict__ Wih,
    const float* __restrict__ Whh, const int* __restrict__ tok,
    const float* __restrict__ emb,
    u16* __restrict__ WoutT, u16* __restrict__ WihT, u16* __restrict__ WhhT,
    u16* __restrict__ embg, float* __restrict__ zbuf)
{
  __shared__ float tile[64][65];
  const int b = blockIdx.x;
  if (b < 8000){
    transpose_tile(Wout, WoutT, 32000, 1024, (b%500)*64, (b/500)*64, tile);
  } else if (b < 9024){
    const int i = b - 8000;
    transpose_tile(Wih, WihT, 4096, 1024, (i&63)*64, (i>>6)*64, tile);
  } else if (b < 10048){
    const int i = b - 9024;
    transpose_tile(Whh, WhhT, 4096, 1024, (i&63)*64, (i>>6)*64, tile);
  } else if (b < 12096){
    const int r = b - 10048, t = threadIdx.x;
    const int trow = tok[r];
    const float4 v = *(const float4*)(emb + (size_t)trow*1024 + t*4);
    ull o = (ull)f2bf(v.x) | ((ull)f2bf(v.y)<<16) | ((ull)f2bf(v.z)<<32) | ((ull)f2bf(v.w)<<48);
    *(ull*)(embg + (size_t)r*1024 + t*4) = o;
  } else {
    const int i = (b - 12096)*256 + threadIdx.x;
    if (i < 65792) zbuf[i] = 0.f;
  }
}

// m97-structure 128x128 bf16 GEMM tile core.
__device__ __forceinline__ void gemm_tile_128(
    const u16* __restrict__ A, const u16* __restrict__ BT,
    int rowbase, int colbase, u16* As, u16* Bs, f32x4 (&acc)[4][4])
{
  const int tid = threadIdx.x;
  const int lane = tid & 63;
  const int wm = (tid>>6)>>1, wn = (tid>>6)&1;
#pragma unroll
  for (int m=0;m<4;++m)
#pragma unroll
    for (int n=0;n<4;++n) acc[m][n] = (f32x4){0.f,0.f,0.f,0.f};

  for (int kb = 0; kb < 1024; kb += 64){
    __syncthreads();
#pragma unroll
    for (int i=0;i<4;++i){
      const int row = i*32 + (tid>>3);
      const int kf  = (tid&7)*16;
      gload_lds16((const char*)(A  + (size_t)(rowbase+row)*1024 + kb) + SWZ(row,kf),
                  (char*)As + (i*256+tid)*16);
      gload_lds16((const char*)(BT + (size_t)(colbase+row)*1024 + kb) + SWZ(row,kf),
                  (char*)Bs + (i*256+tid)*16);
    }
    __syncthreads();
#pragma unroll
    for (int ks=0;ks<2;++ks){
      bf16x8 af[4], bfr[4];
      const int kbyte = ks*64 + (lane>>4)*16;
#pragma unroll
      for (int m=0;m<4;++m){
        const int row = wm*64 + m*16 + (lane&15);
        af[m] = *(const bf16x8*)((const char*)As + row*128 + SWZ(row,kbyte));
      }
#pragma unroll
      for (int n=0;n<4;++n){
        const int col = wn*64 + n*16 + (lane&15);
        bfr[n] = *(const bf16x8*)((const char*)Bs + col*128 + SWZ(col,kbyte));
      }
#pragma unroll
      for (int m=0;m<4;++m)
#pragma unroll
        for (int n=0;n<4;++n)
          acc[m][n] = __builtin_amdgcn_mfma_f32_16x16x32_bf16(af[m], bfr[n], acc[m][n], 0,0,0);
    }
  }
}

// xproj GEMM -> gate-permuted layout:
// xgP[((t*256 + cb)*32 + b)*16 + j*4 + q] = (embg @ WihT^T + b)[t*32+b][q*1024+cb*4+j]
__global__ __launch_bounds__(256,2) void xproj_gemm(
    const u16* __restrict__ Aemb, const u16* __restrict__ WihT,
    const float* __restrict__ bias, float* __restrict__ xgP)
{
  __shared__ u16 As[8192], Bs[8192];
  const int fb = blockIdx.x;
  const int g = (fb&7)*64 + (fb>>3);
  const int ct = g>>4, rt = g&15;
  const int rowbase = rt*128, colbase = ct*128;
  const int tid = threadIdx.x, lane = tid&63;
  const int wm = (tid>>6)>>1, wn = (tid>>6)&1;
  f32x4 acc[4][4];
  gemm_tile_128(Aemb, WihT, rowbase, colbase, As, Bs, acc);
  float bv[4];
#pragma unroll
  for (int n=0;n<4;++n) bv[n] = bias[colbase + wn*64 + n*16 + (lane&15)];
#pragma unroll
  for (int m=0;m<4;++m)
#pragma unroll
    for (int n=0;n<4;++n)
#pragma unroll
      for (int r=0;r<4;++r){
        const int row = rowbase + wm*64 + m*16 + (lane>>4)*4 + r;
        const int col = colbase + wn*64 + n*16 + (lane&15);
        const int tt = row>>5, b = row&31;
        const int q = col>>10, hcol = col&1023;
        xgP[(size_t)(((tt*256 + (hcol>>2))*32 + b)*16 + (hcol&3)*4 + q)] = acc[m][n][r] + bv[n];
      }
}

// ---- Persistent LSTM: 256 blocks x 256 thr (cooperative, 1/CU).
// W_hh in registers; h batch-loaded via inline-asm coherent dwordx4 (one
// pipelined LLC RT). Barrier: per-block flag STORE (no RMW) + wave-0 poll.
__global__ __launch_bounds__(256,1) void lstm_persistent(
    const u16* __restrict__ WhhT, const float* __restrict__ xgP,
    u16* __restrict__ hb0, u16* __restrict__ hb1, u16* __restrict__ hsbf,
    unsigned* __restrict__ slots)
{
  __shared__ float red[4*32*16];  // 8KB
  const int cb = blockIdx.x;
  const int tid = threadIdx.x, lane = tid&63, w = tid>>6;
  const int f = lane & 15;
  const int kfrag = (lane>>4)*8;
  const int gcol = cb*4 + (f&3) + 1024*(f>>2);
  const int bb = tid>>2, j = tid&3;
  const int w8 = w*8;

  // W fragments in registers (32 VGPR), loaded once for all 64 steps.
  bf16x8 wreg[8];
#pragma unroll
  for (int i=0;i<8;++i)
    wreg[i] = *(const bf16x8*)(WhhT + (size_t)gcol*1024 + (w8+i)*32 + kfrag);

  float creg = 0.f;
  // prefetch xg(0)
  float4 x4 = {0.f,0.f,0.f,0.f};
  if (tid < 128)
    x4 = *(const float4*)(xgP + ((size_t)0*256 + cb)*512 + bb*16 + j*4);

  for (int t=0; t<64; ++t){
    const u16* hin = (t&1) ? hb1 : hb0;
    u16*      hout = (t&1) ? hb0 : hb1;

    // ---- 16 coherent loads issued back-to-back (asm: fixed order, live regs)
    const char* p0 = (const char*)(hin + (size_t)f*1024 + w8*32 + kfrag);
    const char* p1 = p0 + 32768;   // row 16+f
    i32x4 h0[8], h1[8];
    h0[0]=gload16_coh<  0>(p0); h0[1]=gload16_coh< 64>(p0);
    h0[2]=gload16_coh<128>(p0); h0[3]=gload16_coh<192>(p0);
    h0[4]=gload16_coh<256>(p0); h0[5]=gload16_coh<320>(p0);
    h0[6]=gload16_coh<384>(p0); h0[7]=gload16_coh<448>(p0);
    h1[0]=gload16_coh<  0>(p1); h1[1]=gload16_coh< 64>(p1);
    h1[2]=gload16_coh<128>(p1); h1[3]=gload16_coh<192>(p1);
    h1[4]=gload16_coh<256>(p1); h1[5]=gload16_coh<320>(p1);
    h1[6]=gload16_coh<384>(p1); h1[7]=gload16_coh<448>(p1);
    asm volatile("s_waitcnt vmcnt(0)" ::: "memory");
    __builtin_amdgcn_sched_barrier(0);

    f32x4 acc0 = (f32x4){0.f,0.f,0.f,0.f};
    f32x4 acc1 = (f32x4){0.f,0.f,0.f,0.f};
#pragma unroll
    for (int i=0;i<8;++i){
      acc0 = __builtin_amdgcn_mfma_f32_16x16x32_bf16(
                 __builtin_bit_cast(bf16x8, h0[i]), wreg[i], acc0, 0,0,0);
      acc1 = __builtin_amdgcn_mfma_f32_16x16x32_bf16(
                 __builtin_bit_cast(bf16x8, h1[i]), wreg[i], acc1, 0,0,0);
    }
#pragma unroll
    for (int r=0;r<4;++r){
      red[w*512 + ((lane>>4)*4 + r)*16 + f]      = acc0[r];
      red[w*512 + (16 + (lane>>4)*4 + r)*16 + f] = acc1[r];
    }
    __syncthreads();
    unsigned hu = 0;
    if (tid < 128){
      float g4[4];
#pragma unroll
      for (int q=0;q<4;++q){
        const int ff = j + 4*q;
        g4[q] = red[0*512 + bb*16 + ff] + red[1*512 + bb*16 + ff]
              + red[2*512 + bb*16 + ff] + red[3*512 + bb*16 + ff];
      }
      g4[0] += x4.x; g4[1] += x4.y; g4[2] += x4.z; g4[3] += x4.w;
      const float iv = sigm(g4[0]), fv = sigm(g4[1]);
      const float gv = tanhf(g4[2]), ov = sigm(g4[3]);
      const float cn = fv*creg + iv*gv;
      const float hv = ov*tanhf(cn);
      creg = cn;
      hu = (unsigned)f2bf(hv);
    }
    // pack 4 consecutive h-cols (j=0..3, same wave) into one 8B value
    const unsigned v1 = __shfl_down(hu, 1, 64);
    const unsigned v2 = __shfl_down(hu, 2, 64);
    const unsigned v3 = __shfl_down(hu, 3, 64);
    const ull p = (ull)hu | ((ull)v1<<16) | ((ull)v2<<32) | ((ull)v3<<48);
    if (tid < 128 && j == 0){
      __hip_atomic_store((ull*)&hout[bb*1024 + cb*4], p,
                         __ATOMIC_RELAXED, __HIP_MEMORY_SCOPE_AGENT);
    }
    if (t < 63){
      __syncthreads();   // every wave drains vmcnt before s_barrier: h at LLC
      if (tid == 0)
        __hip_atomic_store(&slots[cb], (unsigned)(t+1),
                           __ATOMIC_RELAXED, __HIP_MEMORY_SCOPE_AGENT);
      // non-critical work overlaps the poll:
      if (tid < 128 && j == 0)
        *(ull*)&hsbf[(size_t)t*32768 + bb*1024 + cb*4] = p;
      if (tid < 128)
        x4 = *(const float4*)(xgP + ((size_t)(t+1)*256 + cb)*512 + bb*16 + j*4);
      if (tid < 64){
        const unsigned tgt = (unsigned)(t+1);
        const unsigned* sp = slots + tid*4;
        for (;;){
          const unsigned a0 = __hip_atomic_load(sp+0, __ATOMIC_RELAXED, __HIP_MEMORY_SCOPE_AGENT);
          const unsigned a1 = __hip_atomic_load(sp+1, __ATOMIC_RELAXED, __HIP_MEMORY_SCOPE_AGENT);
          const unsigned a2 = __hip_atomic_load(sp+2, __ATOMIC_RELAXED, __HIP_MEMORY_SCOPE_AGENT);
          const unsigned a3 = __hip_atomic_load(sp+3, __ATOMIC_RELAXED, __HIP_MEMORY_SCOPE_AGENT);
          if (__all(a0>=tgt && a1>=tgt && a2>=tgt && a3>=tgt)) break;
          __builtin_amdgcn_s_sleep(1);
        }
      }
      __syncthreads();
    } else {
      if (tid < 128 && j == 0)
        *(ull*)&hsbf[(size_t)63*32768 + bb*1024 + cb*4] = p;
    }
  }
}

// Fallback single-step chain if cooperative launch unsupported.
__global__ __launch_bounds__(256) void lstm_step_mfma(
    const u16* __restrict__ hin, const u16* __restrict__ WhhT,
    const float* __restrict__ xgPt, float* __restrict__ ccell,
    u16* __restrict__ hout, u16* __restrict__ hs_t)
{
  __shared__ float red[4*32*16];
  const int cb = blockIdx.x;
  const int tid = threadIdx.x, lane = tid&63, w = tid>>6;
  const int f = lane & 15;
  const int gcol = cb*4 + (f&3) + 1024*(f>>2);
  const int kfrag = (lane>>4)*8;
  f32x4 acc0 = (f32x4){0.f,0.f,0.f,0.f};
  f32x4 acc1 = (f32x4){0.f,0.f,0.f,0.f};
  const int kb0 = w*256;
#pragma unroll
  for (int kk=0; kk<256; kk+=32){
    const int k = kb0 + kk + kfrag;
    const bf16x8 bfr = *(const bf16x8*)(WhhT + (size_t)gcol*1024 + k);
    const bf16x8 a0  = *(const bf16x8*)(hin + (size_t)f*1024 + k);
    const bf16x8 a1  = *(const bf16x8*)(hin + (size_t)(16+f)*1024 + k);
    acc0 = __builtin_amdgcn_mfma_f32_16x16x32_bf16(a0, bfr, acc0, 0,0,0);
    acc1 = __builtin_amdgcn_mfma_f32_16x16x32_bf16(a1, bfr, acc1, 0,0,0);
  }
#pragma unroll
  for (int r=0;r<4;++r){
    red[w*512 + ((lane>>4)*4 + r)*16 + f]      = acc0[r];
    red[w*512 + (16 + (lane>>4)*4 + r)*16 + f] = acc1[r];
  }
  __syncthreads();
  if (tid < 128){
    const int bb = tid >> 2, j = tid & 3;
    const int hcol = cb*4 + j;
    const float4 x4 = *(const float4*)(xgPt + (size_t)cb*512 + bb*16 + j*4);
    float g4[4];
#pragma unroll
    for (int q=0;q<4;++q){
      const int ff = j + 4*q;
      g4[q] = red[0*512 + bb*16 + ff] + red[1*512 + bb*16 + ff]
            + red[2*512 + bb*16 + ff] + red[3*512 + bb*16 + ff];
    }
    g4[0] += x4.x; g4[1] += x4.y; g4[2] += x4.z; g4[3] += x4.w;
    const float iv = sigm(g4[0]), fv = sigm(g4[1]);
    const float gv = tanhf(g4[2]), ov = sigm(g4[3]);
    const int hidx = bb*1024 + hcol;
    const float cn = fv*ccell[hidx] + iv*gv;
    const float hv = ov*tanhf(cn);
    ccell[hidx] = cn;
    const u16 hb = f2bf(hv);
    hout[hidx] = hb;
    hs_t[hidx] = hb;
  }
}

// logits tile GEMM + fused LSE partials; flat grid (4000) with XCD vt-partition.
__global__ __launch_bounds__(256,2) void logits_gemm_lse(
    const u16* __restrict__ hs, const u16* __restrict__ WoutT,
    const float* __restrict__ bout, const int* __restrict__ gt,
    float* __restrict__ partm, float* __restrict__ parts, float* __restrict__ gtl)
{
  __shared__ u16 As[8192], Bs[8192];
  __shared__ int gts[128];
  const int fb = blockIdx.x;
  const int g = (fb&7)*500 + (fb>>3);   // XCD owns contiguous vt range
  const int vt = g>>4, rt = g&15;
  const int rowbase = rt*128, colbase = vt*128;
  const int tid = threadIdx.x, lane = tid&63;
  const int wm = (tid>>6)>>1, wn = (tid>>6)&1;
  if (tid < 128) gts[tid] = gt[rowbase + tid];
  f32x4 acc[4][4];
  gemm_tile_128(hs, WoutT, rowbase, colbase, As, Bs, acc);
  float bv[4];
#pragma unroll
  for (int n=0;n<4;++n) bv[n] = bout[colbase + wn*64 + n*16 + (lane&15)];
#pragma unroll
  for (int m=0;m<4;++m)
#pragma unroll
    for (int n=0;n<4;++n)
#pragma unroll
      for (int r=0;r<4;++r) acc[m][n][r] += bv[n];
  float rm[4][4], rs[4][4];
#pragma unroll
  for (int m=0;m<4;++m)
#pragma unroll
    for (int r=0;r<4;++r){
      float mx = fmaxf(fmaxf(acc[m][0][r],acc[m][1][r]), fmaxf(acc[m][2][r],acc[m][3][r]));
      mx = fmaxf(mx, __shfl_xor(mx,1,16));
      mx = fmaxf(mx, __shfl_xor(mx,2,16));
      mx = fmaxf(mx, __shfl_xor(mx,4,16));
      mx = fmaxf(mx, __shfl_xor(mx,8,16));
      float sv = __expf(acc[m][0][r]-mx) + __expf(acc[m][1][r]-mx)
               + __expf(acc[m][2][r]-mx) + __expf(acc[m][3][r]-mx);
      sv += __shfl_xor(sv,1,16);
      sv += __shfl_xor(sv,2,16);
      sv += __shfl_xor(sv,4,16);
      sv += __shfl_xor(sv,8,16);
      rm[m][r]=mx; rs[m][r]=sv;
    }
  const int slice = vt*2 + wn;
  if ((lane&15)==0){
#pragma unroll
    for (int m=0;m<4;++m)
#pragma unroll
      for (int r=0;r<4;++r){
        const int rloc = wm*64 + m*16 + (lane>>4)*4 + r;
        partm[(size_t)slice*2048 + rowbase + rloc] = rm[m][r];
        parts[(size_t)slice*2048 + rowbase + rloc] = rs[m][r];
      }
  }
#pragma unroll
  for (int m=0;m<4;++m)
#pragma unroll
    for (int r=0;r<4;++r){
      const int rloc = wm*64 + m*16 + (lane>>4)*4 + r;
      const int gg = gts[rloc] - colbase - wn*64;
      if (gg >= 0 && gg < 64 && (gg&15)==(lane&15)){
        const int n = gg>>4;
        const float val = (n==0)?acc[m][0][r] : (n==1)?acc[m][1][r]
                        : (n==2)?acc[m][2][r] : acc[m][3][r];
        gtl[rowbase+rloc] = val;
      }
    }
}

__global__ __launch_bounds__(256) void lse_finalize2(
    const float* __restrict__ partm, const float* __restrict__ parts,
    const float* __restrict__ gtl, float* __restrict__ nll)
{
  const int r = blockIdx.x*256 + threadIdx.x;
  if (r >= 2048) return;
  float m = -1e30f;
  for (int i=0;i<NSLICE;++i) m = fmaxf(m, partm[(size_t)i*2048 + r]);
  float s = 0.f;
  for (int i=0;i<NSLICE;++i) s += parts[(size_t)i*2048 + r]*__expf(partm[(size_t)i*2048 + r]-m);
  nll[r] = m + logf(s) - gtl[r];
}

__global__ __launch_bounds__(256) void mean_kernel(const float* __restrict__ nll, float* __restrict__ out)
{
  __shared__ float red[4];
  const int t = threadIdx.x;
  float s = 0.f;
  for (int i=t;i<2048;i+=256) s += nll[i];
#pragma unroll
  for (int off=32;off>=1;off>>=1) s += __shfl_down(s, off, 64);
  if ((t&63)==0) red[t>>6]=s;
  __syncthreads();
  if (t==0) out[0] = (red[0]+red[1]+red[2]+red[3]) * (1.0f/2048.0f);
}

extern "C" void kernel_launch(void* const* d_in, const int* in_sizes, int n_in,
                              void* d_out, int out_size, void* d_ws, size_t ws_size,
                              hipStream_t stream)
{
  const int*   tok  = (const int*)d_in[0];
  const int*   gt   = (const int*)d_in[1];
  const float* emb  = (const float*)d_in[2];
  const float* Wih  = (const float*)d_in[3];
  const float* Whh  = (const float*)d_in[4];
  const float* bias = (const float*)d_in[5];
  const float* Wout = (const float*)d_in[6];
  const float* bout = (const float*)d_in[7];
  float* out = (float*)d_out;

  char* base = (char*)d_ws;
  u16*   WoutT = (u16*)base;            base += 65536000;   // 32000*1024*2
  u16*   WihT  = (u16*)base;            base += 8388608;
  u16*   WhhT  = (u16*)base;            base += 8388608;
  u16*   embg  = (u16*)base;            base += 4194304;
  float* xgP   = (float*)base;          base += 33554432;   // 2048*4096*4 (permuted)
  u16*   hsbf  = (u16*)base;            base += 4194304;
  float* cbuf  = (float*)base;          base += 131072;     // fallback c (also zbuf start)
  u16*   hb0   = (u16*)base;            base += 65536;
  u16*   hb1   = (u16*)base;            base += 65536;
  unsigned* slots = (unsigned*)base;    base += 1024;       // 256 per-block flags
  float* partm = (float*)base;          base += 4096000;
  float* parts = (float*)base;          base += 4096000;
  float* gtl   = (float*)base;          base += 8192;
  float* nll   = (float*)base;          base += 8192;

  // one fused prep: Wout/Wih/Whh transposes + emb gather + zero(c,h0,h1,slots)
  prep_kernel<<<12353, 256, 0, stream>>>(Wout, Wih, Whh, tok, emb,
                                         WoutT, WihT, WhhT, embg, cbuf);

  xproj_gemm<<<512, 256, 0, stream>>>(embg, WihT, bias, xgP);

  int coop = 0;
  hipDeviceGetAttribute(&coop, hipDeviceAttributeCooperativeLaunch, 0);
  if (coop){
    void* args[] = {(void*)&WhhT, (void*)&xgP, (void*)&hb0, (void*)&hb1,
                    (void*)&hsbf, (void*)&slots};
    hipLaunchCooperativeKernel((const void*)lstm_persistent,
                               dim3(256), dim3(256), args, 0, stream);
  } else {
    for (int t = 0; t < 64; ++t){
      const u16* hin = (t & 1) ? hb1 : hb0;
      u16*      hout = (t & 1) ? hb0 : hb1;
      lstm_step_mfma<<<256, 256, 0, stream>>>(hin, WhhT,
          xgP + (size_t)t*131072, cbuf, hout, hsbf + (size_t)t*32768);
    }
  }

  logits_gemm_lse<<<4000, 256, 0, stream>>>(hsbf, WoutT, bout, gt, partm, parts, gtl);
  lse_finalize2<<<8, 256, 0, stream>>>(partm, parts, gtl, nll);
  mean_kernel<<<1, 256, 0, stream>>>(nll, out);
}

// Round 11
// 642.738 us; speedup vs baseline: 1.1386x; 1.1386x over previous
//
#include <hip/hip_runtime.h>
#include <hip/hip_bf16.h>

typedef unsigned short u16;
typedef unsigned long long ull;
typedef __attribute__((ext_vector_type(8))) short bf16x8;
typedef __attribute__((ext_vector_type(4))) float f32x4;
typedef __attribute__((ext_vector_type(4))) int i32x4;

#define NSLICE 500   // 250 vocab tiles * 2 wave-columns

__device__ __forceinline__ u16 f2bf(float x){
  unsigned b = __float_as_uint(x);
  return (u16)((b + 0x7FFFu + ((b>>16)&1u)) >> 16);
}
__device__ __forceinline__ float sigm(float x){ return 1.f/(1.f+__expf(-x)); }

__device__ __forceinline__ void gload_lds16(const void* g, void* l){
  __builtin_amdgcn_global_load_lds(
      (const __attribute__((address_space(1))) unsigned int*)g,
      (__attribute__((address_space(3))) unsigned int*)l, 16, 0, 0);
}
// XOR swizzle within a 128B (64 bf16) row: spreads 8 rows over 8 bank slots.
#define SWZ(row, kb) ((kb) ^ (((row)&7)<<4))

// Coherent (LLC) 16B load with literal offset, forced issue order.
template<int OFF>
__device__ __forceinline__ i32x4 gload16_coh(const char* p){
  i32x4 d;
  asm volatile("global_load_dwordx4 %0, %1, off offset:%2 sc0 sc1"
               : "=v"(d) : "v"(p), "n"(OFF) : "memory");
  return d;
}

// ---- fused prep: Wout/Wih/Whh transpose->bf16, emb gather->bf16, zero state.
__device__ __forceinline__ void transpose_tile(
    const float* __restrict__ in, u16* __restrict__ out, int N, int K,
    int nb, int kb, float (*tile)[65])
{
  const int t = threadIdx.x;
#pragma unroll
  for (int i=0;i<4;++i){
    int idx = i*256 + t;          // 1024 float4 chunks
    int k = idx>>4, n4 = idx&15;
    const float4 v = *(const float4*)&in[(size_t)(kb+k)*N + nb + n4*4];
    tile[k][n4*4+0]=v.x; tile[k][n4*4+1]=v.y; tile[k][n4*4+2]=v.z; tile[k][n4*4+3]=v.w;
  }
  __syncthreads();
#pragma unroll
  for (int i=0;i<2;++i){
    int idx = i*256 + t;          // 512 8-elem bf16 chunks
    int n = idx>>3, k8 = idx&7;
    u16 tmp[8];
#pragma unroll
    for (int jj=0;jj<8;++jj) tmp[jj] = f2bf(tile[k8*8+jj][n]);
    *(ulonglong2*)&out[(size_t)(nb+n)*K + kb + k8*8] = *(ulonglong2*)tmp;
  }
}

__global__ __launch_bounds__(256) void prep_kernel(
    const float* __restrict__ Wout, const float* __restrict__ Wih,
    const float* __restrict__ Whh, const int* __restrict__ tok,
    const float* __restrict__ emb,
    u16* __restrict__ WoutT, u16* __restrict__ WihT, u16* __restrict__ WhhT,
    u16* __restrict__ embg, float* __restrict__ zbuf, float* __restrict__ out0)
{
  __shared__ float tile[64][65];
  const int b = blockIdx.x;
  if (b < 8000){
    transpose_tile(Wout, WoutT, 32000, 1024, (b%500)*64, (b/500)*64, tile);
  } else if (b < 9024){
    const int i = b - 8000;
    transpose_tile(Wih, WihT, 4096, 1024, (i&63)*64, (i>>6)*64, tile);
  } else if (b < 10048){
    const int i = b - 9024;
    transpose_tile(Whh, WhhT, 4096, 1024, (i&63)*64, (i>>6)*64, tile);
  } else if (b < 12096){
    const int r = b - 10048, t = threadIdx.x;
    const int trow = tok[r];
    const float4 v = *(const float4*)(emb + (size_t)trow*1024 + t*4);
    ull o = (ull)f2bf(v.x) | ((ull)f2bf(v.y)<<16) | ((ull)f2bf(v.z)<<32) | ((ull)f2bf(v.w)<<48);
    *(ull*)(embg + (size_t)r*1024 + t*4) = o;
  } else {
    const int i = (b - 12096)*256 + threadIdx.x;
    if (i < 65792) zbuf[i] = 0.f;
    if (i == 0) out0[0] = 0.f;
  }
}

// m97-structure 128x128 bf16 GEMM tile core.
__device__ __forceinline__ void gemm_tile_128(
    const u16* __restrict__ A, const u16* __restrict__ BT,
    int rowbase, int colbase, u16* As, u16* Bs, f32x4 (&acc)[4][4])
{
  const int tid = threadIdx.x;
  const int lane = tid & 63;
  const int wm = (tid>>6)>>1, wn = (tid>>6)&1;
#pragma unroll
  for (int m=0;m<4;++m)
#pragma unroll
    for (int n=0;n<4;++n) acc[m][n] = (f32x4){0.f,0.f,0.f,0.f};

  for (int kb = 0; kb < 1024; kb += 64){
    __syncthreads();
#pragma unroll
    for (int i=0;i<4;++i){
      const int row = i*32 + (tid>>3);
      const int kf  = (tid&7)*16;
      gload_lds16((const char*)(A  + (size_t)(rowbase+row)*1024 + kb) + SWZ(row,kf),
                  (char*)As + (i*256+tid)*16);
      gload_lds16((const char*)(BT + (size_t)(colbase+row)*1024 + kb) + SWZ(row,kf),
                  (char*)Bs + (i*256+tid)*16);
    }
    __syncthreads();
#pragma unroll
    for (int ks=0;ks<2;++ks){
      bf16x8 af[4], bfr[4];
      const int kbyte = ks*64 + (lane>>4)*16;
#pragma unroll
      for (int m=0;m<4;++m){
        const int row = wm*64 + m*16 + (lane&15);
        af[m] = *(const bf16x8*)((const char*)As + row*128 + SWZ(row,kbyte));
      }
#pragma unroll
      for (int n=0;n<4;++n){
        const int col = wn*64 + n*16 + (lane&15);
        bfr[n] = *(const bf16x8*)((const char*)Bs + col*128 + SWZ(col,kbyte));
      }
#pragma unroll
      for (int m=0;m<4;++m)
#pragma unroll
        for (int n=0;n<4;++n)
          acc[m][n] = __builtin_amdgcn_mfma_f32_16x16x32_bf16(af[m], bfr[n], acc[m][n], 0,0,0);
    }
  }
}

// xproj GEMM -> gate-permuted layout:
// xgP[((t*256 + cb)*32 + b)*16 + j*4 + q] = (embg @ WihT^T + b)[t*32+b][q*1024+cb*4+j]
__global__ __launch_bounds__(256,2) void xproj_gemm(
    const u16* __restrict__ Aemb, const u16* __restrict__ WihT,
    const float* __restrict__ bias, float* __restrict__ xgP)
{
  __shared__ u16 As[8192], Bs[8192];
  const int fb = blockIdx.x;
  const int g = (fb&7)*64 + (fb>>3);
  const int ct = g>>4, rt = g&15;
  const int rowbase = rt*128, colbase = ct*128;
  const int tid = threadIdx.x, lane = tid&63;
  const int wm = (tid>>6)>>1, wn = (tid>>6)&1;
  f32x4 acc[4][4];
  gemm_tile_128(Aemb, WihT, rowbase, colbase, As, Bs, acc);
  float bv[4];
#pragma unroll
  for (int n=0;n<4;++n) bv[n] = bias[colbase + wn*64 + n*16 + (lane&15)];
#pragma unroll
  for (int m=0;m<4;++m)
#pragma unroll
    for (int n=0;n<4;++n)
#pragma unroll
      for (int r=0;r<4;++r){
        const int row = rowbase + wm*64 + m*16 + (lane>>4)*4 + r;
        const int col = colbase + wn*64 + n*16 + (lane&15);
        const int tt = row>>5, b = row&31;
        const int q = col>>10, hcol = col&1023;
        xgP[(size_t)(((tt*256 + (hcol>>2))*32 + b)*16 + (hcol&3)*4 + q)] = acc[m][n][r] + bv[n];
      }
}

// ---- Persistent LSTM: 256 blocks x 256 thr (cooperative, 1/CU).
// W_hh in registers; h batch-loaded via inline-asm coherent dwordx4 (one
// pipelined LLC RT). Barrier: 8-counter fetch_add + tid0-only poll (R9 form);
// hsbf store + xg prefetch overlap the poll.
__global__ __launch_bounds__(256,1) void lstm_persistent(
    const u16* __restrict__ WhhT, const float* __restrict__ xgP,
    u16* __restrict__ hb0, u16* __restrict__ hb1, u16* __restrict__ hsbf,
    unsigned* __restrict__ bar)
{
  __shared__ float red[4*32*16];  // 8KB
  const int cb = blockIdx.x;
  const int tid = threadIdx.x, lane = tid&63, w = tid>>6;
  const int f = lane & 15;
  const int kfrag = (lane>>4)*8;
  const int gcol = cb*4 + (f&3) + 1024*(f>>2);
  const int bb = tid>>2, j = tid&3;
  const int w8 = w*8;

  // W fragments in registers (32 VGPR), loaded once for all 64 steps.
  bf16x8 wreg[8];
#pragma unroll
  for (int i=0;i<8;++i)
    wreg[i] = *(const bf16x8*)(WhhT + (size_t)gcol*1024 + (w8+i)*32 + kfrag);

  float creg = 0.f;
  // prefetch xg(0)
  float4 x4 = {0.f,0.f,0.f,0.f};
  if (tid < 128)
    x4 = *(const float4*)(xgP + ((size_t)0*256 + cb)*512 + bb*16 + j*4);

  for (int t=0; t<64; ++t){
    const u16* hin = (t&1) ? hb1 : hb0;
    u16*      hout = (t&1) ? hb0 : hb1;

    // ---- 16 coherent loads issued back-to-back (asm: fixed order, live regs)
    const char* p0 = (const char*)(hin + (size_t)f*1024 + w8*32 + kfrag);
    const char* p1 = p0 + 32768;   // row 16+f
    i32x4 h0[8], h1[8];
    h0[0]=gload16_coh<  0>(p0); h0[1]=gload16_coh< 64>(p0);
    h0[2]=gload16_coh<128>(p0); h0[3]=gload16_coh<192>(p0);
    h0[4]=gload16_coh<256>(p0); h0[5]=gload16_coh<320>(p0);
    h0[6]=gload16_coh<384>(p0); h0[7]=gload16_coh<448>(p0);
    h1[0]=gload16_coh<  0>(p1); h1[1]=gload16_coh< 64>(p1);
    h1[2]=gload16_coh<128>(p1); h1[3]=gload16_coh<192>(p1);
    h1[4]=gload16_coh<256>(p1); h1[5]=gload16_coh<320>(p1);
    h1[6]=gload16_coh<384>(p1); h1[7]=gload16_coh<448>(p1);
    asm volatile("s_waitcnt vmcnt(0)" ::: "memory");
    __builtin_amdgcn_sched_barrier(0);

    f32x4 acc0 = (f32x4){0.f,0.f,0.f,0.f};
    f32x4 acc1 = (f32x4){0.f,0.f,0.f,0.f};
#pragma unroll
    for (int i=0;i<8;++i){
      acc0 = __builtin_amdgcn_mfma_f32_16x16x32_bf16(
                 __builtin_bit_cast(bf16x8, h0[i]), wreg[i], acc0, 0,0,0);
      acc1 = __builtin_amdgcn_mfma_f32_16x16x32_bf16(
                 __builtin_bit_cast(bf16x8, h1[i]), wreg[i], acc1, 0,0,0);
    }
#pragma unroll
    for (int r=0;r<4;++r){
      red[w*512 + ((lane>>4)*4 + r)*16 + f]      = acc0[r];
      red[w*512 + (16 + (lane>>4)*4 + r)*16 + f] = acc1[r];
    }
    __syncthreads();
    unsigned hu = 0;
    if (tid < 128){
      float g4[4];
#pragma unroll
      for (int q=0;q<4;++q){
        const int ff = j + 4*q;
        g4[q] = red[0*512 + bb*16 + ff] + red[1*512 + bb*16 + ff]
              + red[2*512 + bb*16 + ff] + red[3*512 + bb*16 + ff];
      }
      g4[0] += x4.x; g4[1] += x4.y; g4[2] += x4.z; g4[3] += x4.w;
      const float iv = sigm(g4[0]), fv = sigm(g4[1]);
      const float gv = tanhf(g4[2]), ov = sigm(g4[3]);
      const float cn = fv*creg + iv*gv;
      const float hv = ov*tanhf(cn);
      creg = cn;
      hu = (unsigned)f2bf(hv);
    }
    // pack 4 consecutive h-cols (j=0..3, same wave) into one 8B value
    const unsigned v1 = __shfl_down(hu, 1, 64);
    const unsigned v2 = __shfl_down(hu, 2, 64);
    const unsigned v3 = __shfl_down(hu, 3, 64);
    const ull p = (ull)hu | ((ull)v1<<16) | ((ull)v2<<32) | ((ull)v3<<48);
    if (tid < 128 && j == 0){
      __hip_atomic_store((ull*)&hout[bb*1024 + cb*4], p,
                         __ATOMIC_RELAXED, __HIP_MEMORY_SCOPE_AGENT);
    }
    if (t < 63){
      __syncthreads();   // every wave drains vmcnt before s_barrier: h at LLC
      if (tid == 0)
        __hip_atomic_fetch_add(&bar[(cb & 7)*32], 1u,
                               __ATOMIC_RELAXED, __HIP_MEMORY_SCOPE_AGENT);
      // non-critical work overlaps the poll:
      if (tid < 128 && j == 0)
        *(ull*)&hsbf[(size_t)t*32768 + bb*1024 + cb*4] = p;
      if (tid < 128)
        x4 = *(const float4*)(xgP + ((size_t)(t+1)*256 + cb)*512 + bb*16 + j*4);
      if (tid == 0){
        const unsigned target = (unsigned)(t+1)*32u;
        for (;;){
          bool ok = true;
#pragma unroll
          for (int i=0;i<8;++i)
            ok &= (__hip_atomic_load(&bar[i*32], __ATOMIC_RELAXED,
                                     __HIP_MEMORY_SCOPE_AGENT) >= target);
          if (ok) break;
          __builtin_amdgcn_s_sleep(2);
        }
        asm volatile("" ::: "memory");
      }
      __syncthreads();
    } else {
      if (tid < 128 && j == 0)
        *(ull*)&hsbf[(size_t)63*32768 + bb*1024 + cb*4] = p;
    }
  }
}

// Fallback single-step chain if cooperative launch unsupported.
__global__ __launch_bounds__(256) void lstm_step_mfma(
    const u16* __restrict__ hin, const u16* __restrict__ WhhT,
    const float* __restrict__ xgPt, float* __restrict__ ccell,
    u16* __restrict__ hout, u16* __restrict__ hs_t)
{
  __shared__ float red[4*32*16];
  const int cb = blockIdx.x;
  const int tid = threadIdx.x, lane = tid&63, w = tid>>6;
  const int f = lane & 15;
  const int gcol = cb*4 + (f&3) + 1024*(f>>2);
  const int kfrag = (lane>>4)*8;
  f32x4 acc0 = (f32x4){0.f,0.f,0.f,0.f};
  f32x4 acc1 = (f32x4){0.f,0.f,0.f,0.f};
  const int kb0 = w*256;
#pragma unroll
  for (int kk=0; kk<256; kk+=32){
    const int k = kb0 + kk + kfrag;
    const bf16x8 bfr = *(const bf16x8*)(WhhT + (size_t)gcol*1024 + k);
    const bf16x8 a0  = *(const bf16x8*)(hin + (size_t)f*1024 + k);
    const bf16x8 a1  = *(const bf16x8*)(hin + (size_t)(16+f)*1024 + k);
    acc0 = __builtin_amdgcn_mfma_f32_16x16x32_bf16(a0, bfr, acc0, 0,0,0);
    acc1 = __builtin_amdgcn_mfma_f32_16x16x32_bf16(a1, bfr, acc1, 0,0,0);
  }
#pragma unroll
  for (int r=0;r<4;++r){
    red[w*512 + ((lane>>4)*4 + r)*16 + f]      = acc0[r];
    red[w*512 + (16 + (lane>>4)*4 + r)*16 + f] = acc1[r];
  }
  __syncthreads();
  if (tid < 128){
    const int bb = tid >> 2, j = tid & 3;
    const int hcol = cb*4 + j;
    const float4 x4 = *(const float4*)(xgPt + (size_t)cb*512 + bb*16 + j*4);
    float g4[4];
#pragma unroll
    for (int q=0;q<4;++q){
      const int ff = j + 4*q;
      g4[q] = red[0*512 + bb*16 + ff] + red[1*512 + bb*16 + ff]
            + red[2*512 + bb*16 + ff] + red[3*512 + bb*16 + ff];
    }
    g4[0] += x4.x; g4[1] += x4.y; g4[2] += x4.z; g4[3] += x4.w;
    const float iv = sigm(g4[0]), fv = sigm(g4[1]);
    const float gv = tanhf(g4[2]), ov = sigm(g4[3]);
    const int hidx = bb*1024 + hcol;
    const float cn = fv*ccell[hidx] + iv*gv;
    const float hv = ov*tanhf(cn);
    ccell[hidx] = cn;
    const u16 hb = f2bf(hv);
    hout[hidx] = hb;
    hs_t[hidx] = hb;
  }
}

// logits tile GEMM + fused LSE partials; flat grid (4000) with XCD vt-partition.
__global__ __launch_bounds__(256,2) void logits_gemm_lse(
    const u16* __restrict__ hs, const u16* __restrict__ WoutT,
    const float* __restrict__ bout, const int* __restrict__ gt,
    float* __restrict__ partm, float* __restrict__ parts, float* __restrict__ gtl)
{
  __shared__ u16 As[8192], Bs[8192];
  __shared__ int gts[128];
  const int fb = blockIdx.x;
  const int g = (fb&7)*500 + (fb>>3);   // XCD owns contiguous vt range
  const int vt = g>>4, rt = g&15;
  const int rowbase = rt*128, colbase = vt*128;
  const int tid = threadIdx.x, lane = tid&63;
  const int wm = (tid>>6)>>1, wn = (tid>>6)&1;
  if (tid < 128) gts[tid] = gt[rowbase + tid];
  f32x4 acc[4][4];
  gemm_tile_128(hs, WoutT, rowbase, colbase, As, Bs, acc);
  float bv[4];
#pragma unroll
  for (int n=0;n<4;++n) bv[n] = bout[colbase + wn*64 + n*16 + (lane&15)];
#pragma unroll
  for (int m=0;m<4;++m)
#pragma unroll
    for (int n=0;n<4;++n)
#pragma unroll
      for (int r=0;r<4;++r) acc[m][n][r] += bv[n];
  float rm[4][4], rs[4][4];
#pragma unroll
  for (int m=0;m<4;++m)
#pragma unroll
    for (int r=0;r<4;++r){
      float mx = fmaxf(fmaxf(acc[m][0][r],acc[m][1][r]), fmaxf(acc[m][2][r],acc[m][3][r]));
      mx = fmaxf(mx, __shfl_xor(mx,1,16));
      mx = fmaxf(mx, __shfl_xor(mx,2,16));
      mx = fmaxf(mx, __shfl_xor(mx,4,16));
      mx = fmaxf(mx, __shfl_xor(mx,8,16));
      float sv = __expf(acc[m][0][r]-mx) + __expf(acc[m][1][r]-mx)
               + __expf(acc[m][2][r]-mx) + __expf(acc[m][3][r]-mx);
      sv += __shfl_xor(sv,1,16);
      sv += __shfl_xor(sv,2,16);
      sv += __shfl_xor(sv,4,16);
      sv += __shfl_xor(sv,8,16);
      rm[m][r]=mx; rs[m][r]=sv;
    }
  const int slice = vt*2 + wn;
  if ((lane&15)==0){
#pragma unroll
    for (int m=0;m<4;++m)
#pragma unroll
      for (int r=0;r<4;++r){
        const int rloc = wm*64 + m*16 + (lane>>4)*4 + r;
        partm[(size_t)slice*2048 + rowbase + rloc] = rm[m][r];
        parts[(size_t)slice*2048 + rowbase + rloc] = rs[m][r];
      }
  }
#pragma unroll
  for (int m=0;m<4;++m)
#pragma unroll
    for (int r=0;r<4;++r){
      const int rloc = wm*64 + m*16 + (lane>>4)*4 + r;
      const int gg = gts[rloc] - colbase - wn*64;
      if (gg >= 0 && gg < 64 && (gg&15)==(lane&15)){
        const int n = gg>>4;
        const float val = (n==0)?acc[m][0][r] : (n==1)?acc[m][1][r]
                        : (n==2)?acc[m][2][r] : acc[m][3][r];
        gtl[rowbase+rloc] = val;
      }
    }
}

// LSE finalize + mean fused: per-row logsumexp, block partial sum, atomicAdd.
__global__ __launch_bounds__(256) void lse_finalize2(
    const float* __restrict__ partm, const float* __restrict__ parts,
    const float* __restrict__ gtl, float* __restrict__ out)
{
  __shared__ float red[4];
  const int r = blockIdx.x*256 + threadIdx.x;
  float m = -1e30f;
  for (int i=0;i<NSLICE;++i) m = fmaxf(m, partm[(size_t)i*2048 + r]);
  float s = 0.f;
  for (int i=0;i<NSLICE;++i) s += parts[(size_t)i*2048 + r]*__expf(partm[(size_t)i*2048 + r]-m);
  float v = (m + logf(s) - gtl[r]) * (1.0f/2048.0f);
#pragma unroll
  for (int off=32;off>=1;off>>=1) v += __shfl_down(v, off, 64);
  if ((threadIdx.x&63)==0) red[threadIdx.x>>6]=v;
  __syncthreads();
  if (threadIdx.x==0) atomicAdd(out, red[0]+red[1]+red[2]+red[3]);
}

extern "C" void kernel_launch(void* const* d_in, const int* in_sizes, int n_in,
                              void* d_out, int out_size, void* d_ws, size_t ws_size,
                              hipStream_t stream)
{
  const int*   tok  = (const int*)d_in[0];
  const int*   gt   = (const int*)d_in[1];
  const float* emb  = (const float*)d_in[2];
  const float* Wih  = (const float*)d_in[3];
  const float* Whh  = (const float*)d_in[4];
  const float* bias = (const float*)d_in[5];
  const float* Wout = (const float*)d_in[6];
  const float* bout = (const float*)d_in[7];
  float* out = (float*)d_out;

  char* base = (char*)d_ws;
  u16*   WoutT = (u16*)base;            base += 65536000;   // 32000*1024*2
  u16*   WihT  = (u16*)base;            base += 8388608;
  u16*   WhhT  = (u16*)base;            base += 8388608;
  u16*   embg  = (u16*)base;            base += 4194304;
  float* xgP   = (float*)base;          base += 33554432;   // 2048*4096*4 (permuted)
  u16*   hsbf  = (u16*)base;            base += 4194304;
  float* cbuf  = (float*)base;          base += 131072;     // fallback c (zbuf start)
  u16*   hb0   = (u16*)base;            base += 65536;
  u16*   hb1   = (u16*)base;            base += 65536;
  unsigned* bar = (unsigned*)base;      base += 1024;       // 8 counters, 128B apart
  float* partm = (float*)base;          base += 4096000;
  float* parts = (float*)base;          base += 4096000;
  float* gtl   = (float*)base;          base += 8192;

  // one fused prep: transposes + emb gather + zero(c,h0,h1,bar) + zero out[0]
  prep_kernel<<<12353, 256, 0, stream>>>(Wout, Wih, Whh, tok, emb,
                                         WoutT, WihT, WhhT, embg, cbuf, out);

  xproj_gemm<<<512, 256, 0, stream>>>(embg, WihT, bias, xgP);

  int coop = 0;
  hipDeviceGetAttribute(&coop, hipDeviceAttributeCooperativeLaunch, 0);
  if (coop){
    void* args[] = {(void*)&WhhT, (void*)&xgP, (void*)&hb0, (void*)&hb1,
                    (void*)&hsbf, (void*)&bar};
    hipLaunchCooperativeKernel((const void*)lstm_persistent,
                               dim3(256), dim3(256), args, 0, stream);
  } else {
    for (int t = 0; t < 64; ++t){
      const u16* hin = (t & 1) ? hb1 : hb0;
      u16*      hout = (t & 1) ? hb0 : hb1;
      lstm_step_mfma<<<256, 256, 0, stream>>>(hin, WhhT,
          xgP + (size_t)t*131072, cbuf, hout, hsbf + (size_t)t*32768);
    }
  }

  logits_gemm_lse<<<4000, 256, 0, stream>>>(hsbf, WoutT, bout, gt, partm, parts, gtl);
  lse_finalize2<<<8, 256, 0, stream>>>(partm, parts, gtl, out);
}

// Round 12
// 570.377 us; speedup vs baseline: 1.2831x; 1.1269x over previous
//
#include <hip/hip_runtime.h>
#include <hip/hip_bf16.h>

typedef unsigned short u16;
typedef unsigned char u8;
typedef unsigned long long ull;
typedef __attribute__((ext_vector_type(8))) short bf16x8;
typedef __attribute__((ext_vector_type(4))) float f32x4;
typedef __attribute__((ext_vector_type(4))) int i32x4;
typedef __attribute__((ext_vector_type(8))) int i32x8;

#define NSLICE 500   // 250 vocab tiles * 2 wave-columns

__device__ __forceinline__ u16 f2bf(float x){
  unsigned b = __float_as_uint(x);
  return (u16)((b + 0x7FFFu + ((b>>16)&1u)) >> 16);
}
__device__ __forceinline__ float sigm(float x){ return 1.f/(1.f+__expf(-x)); }

__device__ __forceinline__ void gload_lds16(const void* g, void* l){
  __builtin_amdgcn_global_load_lds(
      (const __attribute__((address_space(1))) unsigned int*)g,
      (__attribute__((address_space(3))) unsigned int*)l, 16, 0, 0);
}
// XOR swizzle within a 128B row: spreads 8 rows over 8 bank slots.
#define SWZ(row, kb) ((kb) ^ (((row)&7)<<4))

// Coherent (LLC) 16B load with literal offset, forced issue order.
template<int OFF>
__device__ __forceinline__ i32x4 gload16_coh(const char* p){
  i32x4 d;
  asm volatile("global_load_dwordx4 %0, %1, off offset:%2 sc0 sc1"
               : "=v"(d) : "v"(p), "n"(OFF) : "memory");
  return d;
}

// K=128 fp8 MFMA (e4m3 x e4m3, cbsz/blgp=0), unified VGPR operands.
__device__ __forceinline__ f32x4 mfma_f8(i32x8 a, i32x8 b, f32x4 c){
  asm("v_mfma_f32_16x16x128_f8f6f4 %0, %1, %2, %0" : "+v"(c) : "v"(a), "v"(b));
  return c;
}

// ---- fused prep: Wout->fp8^T, Wih/Whh->bf16^T, emb gather->bf16, zero state.
__device__ __forceinline__ void load_tile64(
    const float* __restrict__ in, int N, int nb, int kb, float (*tile)[65])
{
  const int t = threadIdx.x;
#pragma unroll
  for (int i=0;i<4;++i){
    int idx = i*256 + t;          // 1024 float4 chunks
    int k = idx>>4, n4 = idx&15;
    const float4 v = *(const float4*)&in[(size_t)(kb+k)*N + nb + n4*4];
    tile[k][n4*4+0]=v.x; tile[k][n4*4+1]=v.y; tile[k][n4*4+2]=v.z; tile[k][n4*4+3]=v.w;
  }
  __syncthreads();
}

__global__ __launch_bounds__(256) void prep_kernel(
    const float* __restrict__ Wout, const float* __restrict__ Wih,
    const float* __restrict__ Whh, const int* __restrict__ tok,
    const float* __restrict__ emb,
    u8* __restrict__ WoutT8, u16* __restrict__ WihT, u16* __restrict__ WhhT,
    u16* __restrict__ embg, float* __restrict__ zbuf, float* __restrict__ out0)
{
  __shared__ float tile[64][65];
  const int b = blockIdx.x;
  const int t = threadIdx.x;
  if (b < 8000){
    const int nb = (b%500)*64, kb = (b/500)*64;
    load_tile64(Wout, 32000, nb, kb, tile);
#pragma unroll
    for (int i=0;i<2;++i){
      int idx = i*256 + t;
      int n = idx>>3, k8 = idx&7;
      float v0=tile[k8*8+0][n], v1=tile[k8*8+1][n], v2=tile[k8*8+2][n], v3=tile[k8*8+3][n];
      float v4=tile[k8*8+4][n], v5=tile[k8*8+5][n], v6=tile[k8*8+6][n], v7=tile[k8*8+7][n];
      unsigned w0 = __builtin_amdgcn_cvt_pk_fp8_f32(v0, v1, 0, 0);
      w0 = __builtin_amdgcn_cvt_pk_fp8_f32(v2, v3, w0, 1);
      unsigned w1 = __builtin_amdgcn_cvt_pk_fp8_f32(v4, v5, 0, 0);
      w1 = __builtin_amdgcn_cvt_pk_fp8_f32(v6, v7, w1, 1);
      *(ull*)&WoutT8[(size_t)(nb+n)*1024 + kb + k8*8] = (ull)w0 | ((ull)w1<<32);
    }
  } else if (b < 10048){
    const int i = (b < 9024) ? b - 8000 : b - 9024;
    const float* in = (b < 9024) ? Wih : Whh;
    u16* out = (b < 9024) ? WihT : WhhT;
    const int nb = (i&63)*64, kb = (i>>6)*64;
    load_tile64(in, 4096, nb, kb, tile);
#pragma unroll
    for (int ii=0;ii<2;++ii){
      int idx = ii*256 + t;
      int n = idx>>3, k8 = idx&7;
      u16 tmp[8];
#pragma unroll
      for (int jj=0;jj<8;++jj) tmp[jj] = f2bf(tile[k8*8+jj][n]);
      *(ulonglong2*)&out[(size_t)(nb+n)*1024 + kb + k8*8] = *(ulonglong2*)tmp;
    }
  } else if (b < 12096){
    const int r = b - 10048;
    const int trow = tok[r];
    const float4 v = *(const float4*)(emb + (size_t)trow*1024 + t*4);
    ull o = (ull)f2bf(v.x) | ((ull)f2bf(v.y)<<16) | ((ull)f2bf(v.z)<<32) | ((ull)f2bf(v.w)<<48);
    *(ull*)(embg + (size_t)r*1024 + t*4) = o;
  } else {
    const int i = (b - 12096)*256 + t;
    if (i < 65792) zbuf[i] = 0.f;
    if (i == 0) out0[0] = 0.f;
  }
}

// m97-structure 128x128 bf16 GEMM tile core (xproj only now).
__device__ __forceinline__ void gemm_tile_128(
    const u16* __restrict__ A, const u16* __restrict__ BT,
    int rowbase, int colbase, u16* As, u16* Bs, f32x4 (&acc)[4][4])
{
  const int tid = threadIdx.x;
  const int lane = tid & 63;
  const int wm = (tid>>6)>>1, wn = (tid>>6)&1;
#pragma unroll
  for (int m=0;m<4;++m)
#pragma unroll
    for (int n=0;n<4;++n) acc[m][n] = (f32x4){0.f,0.f,0.f,0.f};

  for (int kb = 0; kb < 1024; kb += 64){
    __syncthreads();
#pragma unroll
    for (int i=0;i<4;++i){
      const int row = i*32 + (tid>>3);
      const int kf  = (tid&7)*16;
      gload_lds16((const char*)(A  + (size_t)(rowbase+row)*1024 + kb) + SWZ(row,kf),
                  (char*)As + (i*256+tid)*16);
      gload_lds16((const char*)(BT + (size_t)(colbase+row)*1024 + kb) + SWZ(row,kf),
                  (char*)Bs + (i*256+tid)*16);
    }
    __syncthreads();
#pragma unroll
    for (int ks=0;ks<2;++ks){
      bf16x8 af[4], bfr[4];
      const int kbyte = ks*64 + (lane>>4)*16;
#pragma unroll
      for (int m=0;m<4;++m){
        const int row = wm*64 + m*16 + (lane&15);
        af[m] = *(const bf16x8*)((const char*)As + row*128 + SWZ(row,kbyte));
      }
#pragma unroll
      for (int n=0;n<4;++n){
        const int col = wn*64 + n*16 + (lane&15);
        bfr[n] = *(const bf16x8*)((const char*)Bs + col*128 + SWZ(col,kbyte));
      }
#pragma unroll
      for (int m=0;m<4;++m)
#pragma unroll
        for (int n=0;n<4;++n)
          acc[m][n] = __builtin_amdgcn_mfma_f32_16x16x32_bf16(af[m], bfr[n], acc[m][n], 0,0,0);
    }
  }
}

// xproj GEMM -> gate-permuted layout (unchanged).
__global__ __launch_bounds__(256,2) void xproj_gemm(
    const u16* __restrict__ Aemb, const u16* __restrict__ WihT,
    const float* __restrict__ bias, float* __restrict__ xgP)
{
  __shared__ u16 As[8192], Bs[8192];
  const int fb = blockIdx.x;
  const int g = (fb&7)*64 + (fb>>3);
  const int ct = g>>4, rt = g&15;
  const int rowbase = rt*128, colbase = ct*128;
  const int tid = threadIdx.x, lane = tid&63;
  const int wm = (tid>>6)>>1, wn = (tid>>6)&1;
  f32x4 acc[4][4];
  gemm_tile_128(Aemb, WihT, rowbase, colbase, As, Bs, acc);
  float bv[4];
#pragma unroll
  for (int n=0;n<4;++n) bv[n] = bias[colbase + wn*64 + n*16 + (lane&15)];
#pragma unroll
  for (int m=0;m<4;++m)
#pragma unroll
    for (int n=0;n<4;++n)
#pragma unroll
      for (int r=0;r<4;++r){
        const int row = rowbase + wm*64 + m*16 + (lane>>4)*4 + r;
        const int col = colbase + wn*64 + n*16 + (lane&15);
        const int tt = row>>5, b = row&31;
        const int q = col>>10, hcol = col&1023;
        xgP[(size_t)(((tt*256 + (hcol>>2))*32 + b)*16 + (hcol&3)*4 + q)] = acc[m][n][r] + bv[n];
      }
}

// ---- Persistent LSTM (R11 structure): h bf16 recurrence + fp8 hs side-copy.
__global__ __launch_bounds__(256,1) void lstm_persistent(
    const u16* __restrict__ WhhT, const float* __restrict__ xgP,
    u16* __restrict__ hb0, u16* __restrict__ hb1, u8* __restrict__ hsf8,
    unsigned* __restrict__ bar)
{
  __shared__ float red[4*32*16];  // 8KB
  const int cb = blockIdx.x;
  const int tid = threadIdx.x, lane = tid&63, w = tid>>6;
  const int f = lane & 15;
  const int kfrag = (lane>>4)*8;
  const int gcol = cb*4 + (f&3) + 1024*(f>>2);
  const int bb = tid>>2, j = tid&3;
  const int w8 = w*8;

  bf16x8 wreg[8];
#pragma unroll
  for (int i=0;i<8;++i)
    wreg[i] = *(const bf16x8*)(WhhT + (size_t)gcol*1024 + (w8+i)*32 + kfrag);

  float creg = 0.f;
  float4 x4 = {0.f,0.f,0.f,0.f};
  if (tid < 128)
    x4 = *(const float4*)(xgP + ((size_t)0*256 + cb)*512 + bb*16 + j*4);

  for (int t=0; t<64; ++t){
    const u16* hin = (t&1) ? hb1 : hb0;
    u16*      hout = (t&1) ? hb0 : hb1;

    const char* p0 = (const char*)(hin + (size_t)f*1024 + w8*32 + kfrag);
    const char* p1 = p0 + 32768;
    i32x4 h0[8], h1[8];
    h0[0]=gload16_coh<  0>(p0); h0[1]=gload16_coh< 64>(p0);
    h0[2]=gload16_coh<128>(p0); h0[3]=gload16_coh<192>(p0);
    h0[4]=gload16_coh<256>(p0); h0[5]=gload16_coh<320>(p0);
    h0[6]=gload16_coh<384>(p0); h0[7]=gload16_coh<448>(p0);
    h1[0]=gload16_coh<  0>(p1); h1[1]=gload16_coh< 64>(p1);
    h1[2]=gload16_coh<128>(p1); h1[3]=gload16_coh<192>(p1);
    h1[4]=gload16_coh<256>(p1); h1[5]=gload16_coh<320>(p1);
    h1[6]=gload16_coh<384>(p1); h1[7]=gload16_coh<448>(p1);
    asm volatile("s_waitcnt vmcnt(0)" ::: "memory");
    __builtin_amdgcn_sched_barrier(0);

    f32x4 acc0 = (f32x4){0.f,0.f,0.f,0.f};
    f32x4 acc1 = (f32x4){0.f,0.f,0.f,0.f};
#pragma unroll
    for (int i=0;i<8;++i){
      acc0 = __builtin_amdgcn_mfma_f32_16x16x32_bf16(
                 __builtin_bit_cast(bf16x8, h0[i]), wreg[i], acc0, 0,0,0);
      acc1 = __builtin_amdgcn_mfma_f32_16x16x32_bf16(
                 __builtin_bit_cast(bf16x8, h1[i]), wreg[i], acc1, 0,0,0);
    }
#pragma unroll
    for (int r=0;r<4;++r){
      red[w*512 + ((lane>>4)*4 + r)*16 + f]      = acc0[r];
      red[w*512 + (16 + (lane>>4)*4 + r)*16 + f] = acc1[r];
    }
    __syncthreads();
    unsigned hu = 0, fb8 = 0;
    if (tid < 128){
      float g4[4];
#pragma unroll
      for (int q=0;q<4;++q){
        const int ff = j + 4*q;
        g4[q] = red[0*512 + bb*16 + ff] + red[1*512 + bb*16 + ff]
              + red[2*512 + bb*16 + ff] + red[3*512 + bb*16 + ff];
      }
      g4[0] += x4.x; g4[1] += x4.y; g4[2] += x4.z; g4[3] += x4.w;
      const float iv = sigm(g4[0]), fv = sigm(g4[1]);
      const float gv = tanhf(g4[2]), ov = sigm(g4[3]);
      const float cn = fv*creg + iv*gv;
      const float hv = ov*tanhf(cn);
      creg = cn;
      hu = (unsigned)f2bf(hv);
      fb8 = __builtin_amdgcn_cvt_pk_fp8_f32(hv, 0.f, 0, 0) & 0xffu;
    }
    const unsigned v1 = __shfl_down(hu, 1, 64);
    const unsigned v2 = __shfl_down(hu, 2, 64);
    const unsigned v3 = __shfl_down(hu, 3, 64);
    const ull p = (ull)hu | ((ull)v1<<16) | ((ull)v2<<32) | ((ull)v3<<48);
    const unsigned f1 = __shfl_down(fb8, 1, 64);
    const unsigned f2 = __shfl_down(fb8, 2, 64);
    const unsigned f3 = __shfl_down(fb8, 3, 64);
    const unsigned pf = fb8 | (f1<<8) | (f2<<16) | (f3<<24);
    if (tid < 128 && j == 0){
      __hip_atomic_store((ull*)&hout[bb*1024 + cb*4], p,
                         __ATOMIC_RELAXED, __HIP_MEMORY_SCOPE_AGENT);
    }
    if (t < 63){
      __syncthreads();   // drains vmcnt for all waves: h stores at LLC
      if (tid == 0)
        __hip_atomic_fetch_add(&bar[(cb & 7)*32], 1u,
                               __ATOMIC_RELAXED, __HIP_MEMORY_SCOPE_AGENT);
      // off-critical-path work overlaps the poll:
      if (tid < 128 && j == 0)
        *(unsigned*)&hsf8[(size_t)t*32768 + bb*1024 + cb*4] = pf;
      if (tid < 128)
        x4 = *(const float4*)(xgP + ((size_t)(t+1)*256 + cb)*512 + bb*16 + j*4);
      if (tid == 0){
        const unsigned target = (unsigned)(t+1)*32u;
        for (;;){
          bool ok = true;
#pragma unroll
          for (int i=0;i<8;++i)
            ok &= (__hip_atomic_load(&bar[i*32], __ATOMIC_RELAXED,
                                     __HIP_MEMORY_SCOPE_AGENT) >= target);
          if (ok) break;
          __builtin_amdgcn_s_sleep(2);
        }
        asm volatile("" ::: "memory");
      }
      __syncthreads();
    } else {
      if (tid < 128 && j == 0)
        *(unsigned*)&hsf8[(size_t)63*32768 + bb*1024 + cb*4] = pf;
    }
  }
}

// Fallback single-step chain if cooperative launch unsupported.
__global__ __launch_bounds__(256) void lstm_step_mfma(
    const u16* __restrict__ hin, const u16* __restrict__ WhhT,
    const float* __restrict__ xgPt, float* __restrict__ ccell,
    u16* __restrict__ hout, u8* __restrict__ hs8_t)
{
  __shared__ float red[4*32*16];
  const int cb = blockIdx.x;
  const int tid = threadIdx.x, lane = tid&63, w = tid>>6;
  const int f = lane & 15;
  const int gcol = cb*4 + (f&3) + 1024*(f>>2);
  const int kfrag = (lane>>4)*8;
  f32x4 acc0 = (f32x4){0.f,0.f,0.f,0.f};
  f32x4 acc1 = (f32x4){0.f,0.f,0.f,0.f};
  const int kb0 = w*256;
#pragma unroll
  for (int kk=0; kk<256; kk+=32){
    const int k = kb0 + kk + kfrag;
    const bf16x8 bfr = *(const bf16x8*)(WhhT + (size_t)gcol*1024 + k);
    const bf16x8 a0  = *(const bf16x8*)(hin + (size_t)f*1024 + k);
    const bf16x8 a1  = *(const bf16x8*)(hin + (size_t)(16+f)*1024 + k);
    acc0 = __builtin_amdgcn_mfma_f32_16x16x32_bf16(a0, bfr, acc0, 0,0,0);
    acc1 = __builtin_amdgcn_mfma_f32_16x16x32_bf16(a1, bfr, acc1, 0,0,0);
  }
#pragma unroll
  for (int r=0;r<4;++r){
    red[w*512 + ((lane>>4)*4 + r)*16 + f]      = acc0[r];
    red[w*512 + (16 + (lane>>4)*4 + r)*16 + f] = acc1[r];
  }
  __syncthreads();
  if (tid < 128){
    const int bb = tid >> 2, j = tid & 3;
    const int hcol = cb*4 + j;
    const float4 x4 = *(const float4*)(xgPt + (size_t)cb*512 + bb*16 + j*4);
    float g4[4];
#pragma unroll
    for (int q=0;q<4;++q){
      const int ff = j + 4*q;
      g4[q] = red[0*512 + bb*16 + ff] + red[1*512 + bb*16 + ff]
            + red[2*512 + bb*16 + ff] + red[3*512 + bb*16 + ff];
    }
    g4[0] += x4.x; g4[1] += x4.y; g4[2] += x4.z; g4[3] += x4.w;
    const float iv = sigm(g4[0]), fv = sigm(g4[1]);
    const float gv = tanhf(g4[2]), ov = sigm(g4[3]);
    const int hidx = bb*1024 + hcol;
    const float cn = fv*ccell[hidx] + iv*gv;
    const float hv = ov*tanhf(cn);
    ccell[hidx] = cn;
    hout[hidx] = f2bf(hv);
    hs8_t[hidx] = (u8)(__builtin_amdgcn_cvt_pk_fp8_f32(hv, 0.f, 0, 0) & 0xffu);
  }
}

// logits: fp8 K=128 MFMA tile GEMM + fused LSE partials. 128x128 tile,
// 4 waves, kb-step=128 fp8 (8 iters). Same SWZ/staging byte geometry.
__global__ __launch_bounds__(256,2) void logits_gemm_lse(
    const u8* __restrict__ hs8, const u8* __restrict__ WoutT8,
    const float* __restrict__ bout, const int* __restrict__ gt,
    float* __restrict__ partm, float* __restrict__ parts, float* __restrict__ gtl)
{
  __shared__ u8 As8[16384], Bs8[16384];
  __shared__ int gts[128];
  const int fb = blockIdx.x;
  const int g = (fb&7)*500 + (fb>>3);   // XCD owns contiguous vt range
  const int vt = g>>4, rt = g&15;
  const int rowbase = rt*128, colbase = vt*128;
  const int tid = threadIdx.x, lane = tid&63;
  const int wm = (tid>>6)>>1, wn = (tid>>6)&1;
  if (tid < 128) gts[tid] = gt[rowbase + tid];
  f32x4 acc[4][4];
#pragma unroll
  for (int m=0;m<4;++m)
#pragma unroll
    for (int n=0;n<4;++n) acc[m][n] = (f32x4){0.f,0.f,0.f,0.f};

  for (int kb = 0; kb < 8; ++kb){
    __syncthreads();
#pragma unroll
    for (int i=0;i<4;++i){
      const int row = i*32 + (tid>>3);
      const int kf  = (tid&7)*16;
      gload_lds16((const char*)(hs8    + (size_t)(rowbase+row)*1024 + kb*128) + SWZ(row,kf),
                  (char*)As8 + (i*256+tid)*16);
      gload_lds16((const char*)(WoutT8 + (size_t)(colbase+row)*1024 + kb*128) + SWZ(row,kf),
                  (char*)Bs8 + (i*256+tid)*16);
    }
    __syncthreads();
    const int kbyte = (lane>>4)*32;
    i32x8 af[4], bfr[4];
#pragma unroll
    for (int m=0;m<4;++m){
      const int row = wm*64 + m*16 + (lane&15);
      union { i32x8 v8; i32x4 v4[2]; } u;
      u.v4[0] = *(const i32x4*)(As8 + row*128 + SWZ(row, kbyte));
      u.v4[1] = *(const i32x4*)(As8 + row*128 + SWZ(row, kbyte+16));
      af[m] = u.v8;
    }
#pragma unroll
    for (int n=0;n<4;++n){
      const int col = wn*64 + n*16 + (lane&15);
      union { i32x8 v8; i32x4 v4[2]; } u;
      u.v4[0] = *(const i32x4*)(Bs8 + col*128 + SWZ(col, kbyte));
      u.v4[1] = *(const i32x4*)(Bs8 + col*128 + SWZ(col, kbyte+16));
      bfr[n] = u.v8;
    }
#pragma unroll
    for (int m=0;m<4;++m)
#pragma unroll
      for (int n=0;n<4;++n)
        acc[m][n] = mfma_f8(af[m], bfr[n], acc[m][n]);
  }

  float bv[4];
#pragma unroll
  for (int n=0;n<4;++n) bv[n] = bout[colbase + wn*64 + n*16 + (lane&15)];
#pragma unroll
  for (int m=0;m<4;++m)
#pragma unroll
    for (int n=0;n<4;++n)
#pragma unroll
      for (int r=0;r<4;++r) acc[m][n][r] += bv[n];
  float rm[4][4], rs[4][4];
#pragma unroll
  for (int m=0;m<4;++m)
#pragma unroll
    for (int r=0;r<4;++r){
      float mx = fmaxf(fmaxf(acc[m][0][r],acc[m][1][r]), fmaxf(acc[m][2][r],acc[m][3][r]));
      mx = fmaxf(mx, __shfl_xor(mx,1,16));
      mx = fmaxf(mx, __shfl_xor(mx,2,16));
      mx = fmaxf(mx, __shfl_xor(mx,4,16));
      mx = fmaxf(mx, __shfl_xor(mx,8,16));
      float sv = __expf(acc[m][0][r]-mx) + __expf(acc[m][1][r]-mx)
               + __expf(acc[m][2][r]-mx) + __expf(acc[m][3][r]-mx);
      sv += __shfl_xor(sv,1,16);
      sv += __shfl_xor(sv,2,16);
      sv += __shfl_xor(sv,4,16);
      sv += __shfl_xor(sv,8,16);
      rm[m][r]=mx; rs[m][r]=sv;
    }
  const int slice = vt*2 + wn;
  if ((lane&15)==0){
#pragma unroll
    for (int m=0;m<4;++m)
#pragma unroll
      for (int r=0;r<4;++r){
        const int rloc = wm*64 + m*16 + (lane>>4)*4 + r;
        partm[(size_t)slice*2048 + rowbase + rloc] = rm[m][r];
        parts[(size_t)slice*2048 + rowbase + rloc] = rs[m][r];
      }
  }
#pragma unroll
  for (int m=0;m<4;++m)
#pragma unroll
    for (int r=0;r<4;++r){
      const int rloc = wm*64 + m*16 + (lane>>4)*4 + r;
      const int gg = gts[rloc] - colbase - wn*64;
      if (gg >= 0 && gg < 64 && (gg&15)==(lane&15)){
        const int n = gg>>4;
        const float val = (n==0)?acc[m][0][r] : (n==1)?acc[m][1][r]
                        : (n==2)?acc[m][2][r] : acc[m][3][r];
        gtl[rowbase+rloc] = val;
      }
    }
}

// LSE finalize + mean fused.
__global__ __launch_bounds__(256) void lse_finalize2(
    const float* __restrict__ partm, const float* __restrict__ parts,
    const float* __restrict__ gtl, float* __restrict__ out)
{
  __shared__ float red[4];
  const int r = blockIdx.x*256 + threadIdx.x;
  float m = -1e30f;
  for (int i=0;i<NSLICE;++i) m = fmaxf(m, partm[(size_t)i*2048 + r]);
  float s = 0.f;
  for (int i=0;i<NSLICE;++i) s += parts[(size_t)i*2048 + r]*__expf(partm[(size_t)i*2048 + r]-m);
  float v = (m + logf(s) - gtl[r]) * (1.0f/2048.0f);
#pragma unroll
  for (int off=32;off>=1;off>>=1) v += __shfl_down(v, off, 64);
  if ((threadIdx.x&63)==0) red[threadIdx.x>>6]=v;
  __syncthreads();
  if (threadIdx.x==0) atomicAdd(out, red[0]+red[1]+red[2]+red[3]);
}

extern "C" void kernel_launch(void* const* d_in, const int* in_sizes, int n_in,
                              void* d_out, int out_size, void* d_ws, size_t ws_size,
                              hipStream_t stream)
{
  const int*   tok  = (const int*)d_in[0];
  const int*   gt   = (const int*)d_in[1];
  const float* emb  = (const float*)d_in[2];
  const float* Wih  = (const float*)d_in[3];
  const float* Whh  = (const float*)d_in[4];
  const float* bias = (const float*)d_in[5];
  const float* Wout = (const float*)d_in[6];
  const float* bout = (const float*)d_in[7];
  float* out = (float*)d_out;

  char* base = (char*)d_ws;
  u8*    WoutT8 = (u8*)base;            base += 32768000;   // 32000*1024*1
  u16*   WihT  = (u16*)base;            base += 8388608;
  u16*   WhhT  = (u16*)base;            base += 8388608;
  u16*   embg  = (u16*)base;            base += 4194304;
  float* xgP   = (float*)base;          base += 33554432;   // 2048*4096*4 (permuted)
  u8*    hsf8  = (u8*)base;             base += 2097152;    // 2048*1024*1
  float* cbuf  = (float*)base;          base += 131072;     // fallback c (zbuf start)
  u16*   hb0   = (u16*)base;            base += 65536;
  u16*   hb1   = (u16*)base;            base += 65536;
  unsigned* bar = (unsigned*)base;      base += 1024;       // 8 counters, 128B apart
  float* partm = (float*)base;          base += 4096000;
  float* parts = (float*)base;          base += 4096000;
  float* gtl   = (float*)base;          base += 8192;

  // one fused prep: transposes (Wout->fp8) + emb gather + zero(c,h0,h1,bar,out)
  prep_kernel<<<12353, 256, 0, stream>>>(Wout, Wih, Whh, tok, emb,
                                         WoutT8, WihT, WhhT, embg, cbuf, out);

  xproj_gemm<<<512, 256, 0, stream>>>(embg, WihT, bias, xgP);

  int coop = 0;
  hipDeviceGetAttribute(&coop, hipDeviceAttributeCooperativeLaunch, 0);
  if (coop){
    void* args[] = {(void*)&WhhT, (void*)&xgP, (void*)&hb0, (void*)&hb1,
                    (void*)&hsf8, (void*)&bar};
    hipLaunchCooperativeKernel((const void*)lstm_persistent,
                               dim3(256), dim3(256), args, 0, stream);
  } else {
    for (int t = 0; t < 64; ++t){
      const u16* hin = (t & 1) ? hb1 : hb0;
      u16*      hout = (t & 1) ? hb0 : hb1;
      lstm_step_mfma<<<256, 256, 0, stream>>>(hin, WhhT,
          xgP + (size_t)t*131072, cbuf, hout, hsf8 + (size_t)t*32768);
    }
  }

  logits_gemm_lse<<<4000, 256, 0, stream>>>(hsf8, WoutT8, bout, gt, partm, parts, gtl);
  lse_finalize2<<<8, 256, 0, stream>>>(partm, parts, gtl, out);
}

// Round 13
// 529.109 us; speedup vs baseline: 1.3832x; 1.0780x over previous
//
#include <hip/hip_runtime.h>
#include <hip/hip_bf16.h>

typedef unsigned short u16;
typedef unsigned char u8;
typedef unsigned long long ull;
typedef __attribute__((ext_vector_type(8))) short bf16x8;
typedef __attribute__((ext_vector_type(4))) float f32x4;
typedef __attribute__((ext_vector_type(4))) int i32x4;
typedef __attribute__((ext_vector_type(8))) int i32x8;

#define NSLICE 500   // 250 vocab tiles * 2 wave-columns

__device__ __forceinline__ u16 f2bf(float x){
  unsigned b = __float_as_uint(x);
  return (u16)((b + 0x7FFFu + ((b>>16)&1u)) >> 16);
}
__device__ __forceinline__ float sigm(float x){ return 1.f/(1.f+__expf(-x)); }

__device__ __forceinline__ void gload_lds16(const void* g, void* l){
  __builtin_amdgcn_global_load_lds(
      (const __attribute__((address_space(1))) unsigned int*)g,
      (__attribute__((address_space(3))) unsigned int*)l, 16, 0, 0);
}
// XOR swizzle within a 128B row: spreads 8 rows over 8 bank slots.
#define SWZ(row, kb) ((kb) ^ (((row)&7)<<4))

// Coherent (LLC) 16B load with literal offset, forced issue order.
template<int OFF>
__device__ __forceinline__ i32x4 gload16_coh(const char* p){
  i32x4 d;
  asm volatile("global_load_dwordx4 %0, %1, off offset:%2 sc0 sc1"
               : "=v"(d) : "v"(p), "n"(OFF) : "memory");
  return d;
}

// K=128 fp8 MFMA (e4m3 x e4m3, cbsz/blgp=0), unified VGPR operands.
__device__ __forceinline__ f32x4 mfma_f8(i32x8 a, i32x8 b, f32x4 c){
  asm("v_mfma_f32_16x16x128_f8f6f4 %0, %1, %2, %0" : "+v"(c) : "v"(a), "v"(b));
  return c;
}

// ---- prep: Wih/Whh transpose->bf16, emb gather->bf16, zero state.
// (Wout->fp8 transpose is folded into the LSTM's barrier idle time.)
__device__ __forceinline__ void load_tile64(
    const float* __restrict__ in, int N, int nb, int kb, float (*tile)[65])
{
  const int t = threadIdx.x;
#pragma unroll
  for (int i=0;i<4;++i){
    int idx = i*256 + t;          // 1024 float4 chunks
    int k = idx>>4, n4 = idx&15;
    const float4 v = *(const float4*)&in[(size_t)(kb+k)*N + nb + n4*4];
    tile[k][n4*4+0]=v.x; tile[k][n4*4+1]=v.y; tile[k][n4*4+2]=v.z; tile[k][n4*4+3]=v.w;
  }
  __syncthreads();
}

__global__ __launch_bounds__(256) void prep_kernel(
    const float* __restrict__ Wih, const float* __restrict__ Whh,
    const int* __restrict__ tok, const float* __restrict__ emb,
    u16* __restrict__ WihT, u16* __restrict__ WhhT,
    u16* __restrict__ embg, float* __restrict__ zbuf, float* __restrict__ out0)
{
  __shared__ float tile[64][65];
  const int b = blockIdx.x;
  const int t = threadIdx.x;
  if (b < 2048){
    const int i = (b < 1024) ? b : b - 1024;
    const float* in = (b < 1024) ? Wih : Whh;
    u16* out = (b < 1024) ? WihT : WhhT;
    const int nb = (i&63)*64, kb = (i>>6)*64;
    load_tile64(in, 4096, nb, kb, tile);
#pragma unroll
    for (int ii=0;ii<2;++ii){
      int idx = ii*256 + t;
      int n = idx>>3, k8 = idx&7;
      u16 tmp[8];
#pragma unroll
      for (int jj=0;jj<8;++jj) tmp[jj] = f2bf(tile[k8*8+jj][n]);
      *(ulonglong2*)&out[(size_t)(nb+n)*1024 + kb + k8*8] = *(ulonglong2*)tmp;
    }
  } else if (b < 4096){
    const int r = b - 2048;
    const int trow = tok[r];
    const float4 v = *(const float4*)(emb + (size_t)trow*1024 + t*4);
    ull o = (ull)f2bf(v.x) | ((ull)f2bf(v.y)<<16) | ((ull)f2bf(v.z)<<32) | ((ull)f2bf(v.w)<<48);
    *(ull*)(embg + (size_t)r*1024 + t*4) = o;
  } else {
    const int i = (b - 4096)*256 + t;
    if (i < 65792) zbuf[i] = 0.f;
    if (i == 0) out0[0] = 0.f;
  }
}

// m97-structure 128x128 bf16 GEMM tile core (xproj only).
__device__ __forceinline__ void gemm_tile_128(
    const u16* __restrict__ A, const u16* __restrict__ BT,
    int rowbase, int colbase, u16* As, u16* Bs, f32x4 (&acc)[4][4])
{
  const int tid = threadIdx.x;
  const int lane = tid & 63;
  const int wm = (tid>>6)>>1, wn = (tid>>6)&1;
#pragma unroll
  for (int m=0;m<4;++m)
#pragma unroll
    for (int n=0;n<4;++n) acc[m][n] = (f32x4){0.f,0.f,0.f,0.f};

  for (int kb = 0; kb < 1024; kb += 64){
    __syncthreads();
#pragma unroll
    for (int i=0;i<4;++i){
      const int row = i*32 + (tid>>3);
      const int kf  = (tid&7)*16;
      gload_lds16((const char*)(A  + (size_t)(rowbase+row)*1024 + kb) + SWZ(row,kf),
                  (char*)As + (i*256+tid)*16);
      gload_lds16((const char*)(BT + (size_t)(colbase+row)*1024 + kb) + SWZ(row,kf),
                  (char*)Bs + (i*256+tid)*16);
    }
    __syncthreads();
#pragma unroll
    for (int ks=0;ks<2;++ks){
      bf16x8 af[4], bfr[4];
      const int kbyte = ks*64 + (lane>>4)*16;
#pragma unroll
      for (int m=0;m<4;++m){
        const int row = wm*64 + m*16 + (lane&15);
        af[m] = *(const bf16x8*)((const char*)As + row*128 + SWZ(row,kbyte));
      }
#pragma unroll
      for (int n=0;n<4;++n){
        const int col = wn*64 + n*16 + (lane&15);
        bfr[n] = *(const bf16x8*)((const char*)Bs + col*128 + SWZ(col,kbyte));
      }
#pragma unroll
      for (int m=0;m<4;++m)
#pragma unroll
        for (int n=0;n<4;++n)
          acc[m][n] = __builtin_amdgcn_mfma_f32_16x16x32_bf16(af[m], bfr[n], acc[m][n], 0,0,0);
    }
  }
}

// xproj GEMM -> gate-permuted layout (unchanged).
__global__ __launch_bounds__(256,2) void xproj_gemm(
    const u16* __restrict__ Aemb, const u16* __restrict__ WihT,
    const float* __restrict__ bias, float* __restrict__ xgP)
{
  __shared__ u16 As[8192], Bs[8192];
  const int fb = blockIdx.x;
  const int g = (fb&7)*64 + (fb>>3);
  const int ct = g>>4, rt = g&15;
  const int rowbase = rt*128, colbase = ct*128;
  const int tid = threadIdx.x, lane = tid&63;
  const int wm = (tid>>6)>>1, wn = (tid>>6)&1;
  f32x4 acc[4][4];
  gemm_tile_128(Aemb, WihT, rowbase, colbase, As, Bs, acc);
  float bv[4];
#pragma unroll
  for (int n=0;n<4;++n) bv[n] = bias[colbase + wn*64 + n*16 + (lane&15)];
#pragma unroll
  for (int m=0;m<4;++m)
#pragma unroll
    for (int n=0;n<4;++n)
#pragma unroll
      for (int r=0;r<4;++r){
        const int row = rowbase + wm*64 + m*16 + (lane>>4)*4 + r;
        const int col = colbase + wn*64 + n*16 + (lane&15);
        const int tt = row>>5, b = row&31;
        const int q = col>>10, hcol = col&1023;
        xgP[(size_t)(((tt*256 + (hcol>>2))*32 + b)*16 + (hcol&3)*4 + q)] = acc[m][n][r] + bv[n];
      }
}

// ---- Persistent LSTM (regular launch; 256 blocks <= 256 CUs co-resident).
// R11 barrier (8-counter fetch_add + tid0 poll). Wout->fp8 transpose folded
// into the barrier idle window: even t = tile load to LDS, odd t = fp8 store.
__global__ __launch_bounds__(256,1) void lstm_persistent(
    const u16* __restrict__ WhhT, const float* __restrict__ xgP,
    u16* __restrict__ hb0, u16* __restrict__ hb1, u8* __restrict__ hsf8,
    unsigned* __restrict__ bar,
    const float* __restrict__ Wout, u8* __restrict__ WoutT8)
{
  __shared__ float red[4*32*16];   // 8KB
  __shared__ float tile[64][65];   // 16.6KB (Wout transpose staging)
  const int cb = blockIdx.x;
  const int tid = threadIdx.x, lane = tid&63, w = tid>>6;
  const int f = lane & 15;
  const int kfrag = (lane>>4)*8;
  const int gcol = cb*4 + (f&3) + 1024*(f>>2);
  const int bb = tid>>2, j = tid&3;
  const int w8 = w*8;

  bf16x8 wreg[8];
#pragma unroll
  for (int i=0;i<8;++i)
    wreg[i] = *(const bf16x8*)(WhhT + (size_t)gcol*1024 + (w8+i)*32 + kfrag);

  float creg = 0.f;
  float4 x4 = {0.f,0.f,0.f,0.f};
  if (tid < 128)
    x4 = *(const float4*)(xgP + ((size_t)0*256 + cb)*512 + bb*16 + j*4);

  for (int t=0; t<64; ++t){
    const u16* hin = (t&1) ? hb1 : hb0;
    u16*      hout = (t&1) ? hb0 : hb1;

    const char* p0 = (const char*)(hin + (size_t)f*1024 + w8*32 + kfrag);
    const char* p1 = p0 + 32768;
    i32x4 h0[8], h1[8];
    h0[0]=gload16_coh<  0>(p0); h0[1]=gload16_coh< 64>(p0);
    h0[2]=gload16_coh<128>(p0); h0[3]=gload16_coh<192>(p0);
    h0[4]=gload16_coh<256>(p0); h0[5]=gload16_coh<320>(p0);
    h0[6]=gload16_coh<384>(p0); h0[7]=gload16_coh<448>(p0);
    h1[0]=gload16_coh<  0>(p1); h1[1]=gload16_coh< 64>(p1);
    h1[2]=gload16_coh<128>(p1); h1[3]=gload16_coh<192>(p1);
    h1[4]=gload16_coh<256>(p1); h1[5]=gload16_coh<320>(p1);
    h1[6]=gload16_coh<384>(p1); h1[7]=gload16_coh<448>(p1);
    asm volatile("s_waitcnt vmcnt(0)" ::: "memory");
    __builtin_amdgcn_sched_barrier(0);

    f32x4 acc0 = (f32x4){0.f,0.f,0.f,0.f};
    f32x4 acc1 = (f32x4){0.f,0.f,0.f,0.f};
#pragma unroll
    for (int i=0;i<8;++i){
      acc0 = __builtin_amdgcn_mfma_f32_16x16x32_bf16(
                 __builtin_bit_cast(bf16x8, h0[i]), wreg[i], acc0, 0,0,0);
      acc1 = __builtin_amdgcn_mfma_f32_16x16x32_bf16(
                 __builtin_bit_cast(bf16x8, h1[i]), wreg[i], acc1, 0,0,0);
    }
#pragma unroll
    for (int r=0;r<4;++r){
      red[w*512 + ((lane>>4)*4 + r)*16 + f]      = acc0[r];
      red[w*512 + (16 + (lane>>4)*4 + r)*16 + f] = acc1[r];
    }
    __syncthreads();
    unsigned hu = 0, fb8 = 0;
    if (tid < 128){
      float g4[4];
#pragma unroll
      for (int q=0;q<4;++q){
        const int ff = j + 4*q;
        g4[q] = red[0*512 + bb*16 + ff] + red[1*512 + bb*16 + ff]
              + red[2*512 + bb*16 + ff] + red[3*512 + bb*16 + ff];
      }
      g4[0] += x4.x; g4[1] += x4.y; g4[2] += x4.z; g4[3] += x4.w;
      const float iv = sigm(g4[0]), fv = sigm(g4[1]);
      const float gv = tanhf(g4[2]), ov = sigm(g4[3]);
      const float cn = fv*creg + iv*gv;
      const float hv = ov*tanhf(cn);
      creg = cn;
      hu = (unsigned)f2bf(hv);
      fb8 = __builtin_amdgcn_cvt_pk_fp8_f32(hv, 0.f, 0, 0) & 0xffu;
    }
    const unsigned v1 = __shfl_down(hu, 1, 64);
    const unsigned v2 = __shfl_down(hu, 2, 64);
    const unsigned v3 = __shfl_down(hu, 3, 64);
    const ull p = (ull)hu | ((ull)v1<<16) | ((ull)v2<<32) | ((ull)v3<<48);
    const unsigned f1 = __shfl_down(fb8, 1, 64);
    const unsigned f2 = __shfl_down(fb8, 2, 64);
    const unsigned f3 = __shfl_down(fb8, 3, 64);
    const unsigned pf = fb8 | (f1<<8) | (f2<<16) | (f3<<24);
    if (tid < 128 && j == 0){
      __hip_atomic_store((ull*)&hout[bb*1024 + cb*4], p,
                         __ATOMIC_RELAXED, __HIP_MEMORY_SCOPE_AGENT);
    }
    // Wout transpose tile for this step pair (s = t>>1):
    const int tile_id = (t>>1)*256 + cb;
    if (t < 63){
      __syncthreads();   // drains vmcnt for all waves: h stores at LLC
      if (tid == 0)
        __hip_atomic_fetch_add(&bar[(cb & 7)*32], 1u,
                               __ATOMIC_RELAXED, __HIP_MEMORY_SCOPE_AGENT);
      // ---- off-critical-path work overlaps flag propagation ----
      if (tid < 128 && j == 0)
        *(unsigned*)&hsf8[(size_t)t*32768 + bb*1024 + cb*4] = pf;
      if (tid < 128)
        x4 = *(const float4*)(xgP + ((size_t)(t+1)*256 + cb)*512 + bb*16 + j*4);
      if (tile_id < 8000){
        const int nb = (tile_id % 500)*64, kb = (tile_id / 500)*64;
        if ((t & 1) == 0){
          // load phase: 64x64 f32 tile -> LDS (coalesced float4)
#pragma unroll
          for (int i=0;i<4;++i){
            int idx = i*256 + tid;
            int k = idx>>4, n4 = idx&15;
            const float4 v = *(const float4*)&Wout[(size_t)(kb+k)*32000 + nb + n4*4];
            tile[k][n4*4+0]=v.x; tile[k][n4*4+1]=v.y;
            tile[k][n4*4+2]=v.z; tile[k][n4*4+3]=v.w;
          }
        } else {
          // store phase: convert + fp8 store (tile was synced last step)
#pragma unroll
          for (int i=0;i<2;++i){
            int idx = i*256 + tid;
            int n = idx>>3, k8 = idx&7;
            float v0=tile[k8*8+0][n], s1=tile[k8*8+1][n], s2=tile[k8*8+2][n], s3=tile[k8*8+3][n];
            float v4=tile[k8*8+4][n], s5=tile[k8*8+5][n], s6=tile[k8*8+6][n], s7=tile[k8*8+7][n];
            unsigned w0 = __builtin_amdgcn_cvt_pk_fp8_f32(v0, s1, 0, 0);
            w0 = __builtin_amdgcn_cvt_pk_fp8_f32(s2, s3, w0, 1);
            unsigned w1 = __builtin_amdgcn_cvt_pk_fp8_f32(v4, s5, 0, 0);
            w1 = __builtin_amdgcn_cvt_pk_fp8_f32(s6, s7, w1, 1);
            *(ull*)&WoutT8[(size_t)(nb+n)*1024 + kb + k8*8] = (ull)w0 | ((ull)w1<<32);
          }
        }
      }
      if (tid == 0){
        const unsigned target = (unsigned)(t+1)*32u;
        for (;;){
          bool ok = true;
#pragma unroll
          for (int i=0;i<8;++i)
            ok &= (__hip_atomic_load(&bar[i*32], __ATOMIC_RELAXED,
                                     __HIP_MEMORY_SCOPE_AGENT) >= target);
          if (ok) break;
          __builtin_amdgcn_s_sleep(2);
        }
        asm volatile("" ::: "memory");
      }
      __syncthreads();
    } else {
      // t == 63: final hs store + last transpose store phase (s=31, cb<64)
      if (tid < 128 && j == 0)
        *(unsigned*)&hsf8[(size_t)63*32768 + bb*1024 + cb*4] = pf;
      if (tile_id < 8000){
        const int nb = (tile_id % 500)*64, kb = (tile_id / 500)*64;
#pragma unroll
        for (int i=0;i<2;++i){
          int idx = i*256 + tid;
          int n = idx>>3, k8 = idx&7;
          float v0=tile[k8*8+0][n], s1=tile[k8*8+1][n], s2=tile[k8*8+2][n], s3=tile[k8*8+3][n];
          float v4=tile[k8*8+4][n], s5=tile[k8*8+5][n], s6=tile[k8*8+6][n], s7=tile[k8*8+7][n];
          unsigned w0 = __builtin_amdgcn_cvt_pk_fp8_f32(v0, s1, 0, 0);
          w0 = __builtin_amdgcn_cvt_pk_fp8_f32(s2, s3, w0, 1);
          unsigned w1 = __builtin_amdgcn_cvt_pk_fp8_f32(v4, s5, 0, 0);
          w1 = __builtin_amdgcn_cvt_pk_fp8_f32(s6, s7, w1, 1);
          *(ull*)&WoutT8[(size_t)(nb+n)*1024 + kb + k8*8] = (ull)w0 | ((ull)w1<<32);
        }
      }
    }
  }
}

// logits: fp8 K=128 MFMA tile GEMM + fused LSE partials (unchanged).
__global__ __launch_bounds__(256,2) void logits_gemm_lse(
    const u8* __restrict__ hs8, const u8* __restrict__ WoutT8,
    const float* __restrict__ bout, const int* __restrict__ gt,
    float* __restrict__ partm, float* __restrict__ parts, float* __restrict__ gtl)
{
  __shared__ u8 As8[16384], Bs8[16384];
  __shared__ int gts[128];
  const int fb = blockIdx.x;
  const int g = (fb&7)*500 + (fb>>3);   // XCD owns contiguous vt range
  const int vt = g>>4, rt = g&15;
  const int rowbase = rt*128, colbase = vt*128;
  const int tid = threadIdx.x, lane = tid&63;
  const int wm = (tid>>6)>>1, wn = (tid>>6)&1;
  if (tid < 128) gts[tid] = gt[rowbase + tid];
  f32x4 acc[4][4];
#pragma unroll
  for (int m=0;m<4;++m)
#pragma unroll
    for (int n=0;n<4;++n) acc[m][n] = (f32x4){0.f,0.f,0.f,0.f};

  for (int kb = 0; kb < 8; ++kb){
    __syncthreads();
#pragma unroll
    for (int i=0;i<4;++i){
      const int row = i*32 + (tid>>3);
      const int kf  = (tid&7)*16;
      gload_lds16((const char*)(hs8    + (size_t)(rowbase+row)*1024 + kb*128) + SWZ(row,kf),
                  (char*)As8 + (i*256+tid)*16);
      gload_lds16((const char*)(WoutT8 + (size_t)(colbase+row)*1024 + kb*128) + SWZ(row,kf),
                  (char*)Bs8 + (i*256+tid)*16);
    }
    __syncthreads();
    const int kbyte = (lane>>4)*32;
    i32x8 af[4], bfr[4];
#pragma unroll
    for (int m=0;m<4;++m){
      const int row = wm*64 + m*16 + (lane&15);
      union { i32x8 v8; i32x4 v4[2]; } u;
      u.v4[0] = *(const i32x4*)(As8 + row*128 + SWZ(row, kbyte));
      u.v4[1] = *(const i32x4*)(As8 + row*128 + SWZ(row, kbyte+16));
      af[m] = u.v8;
    }
#pragma unroll
    for (int n=0;n<4;++n){
      const int col = wn*64 + n*16 + (lane&15);
      union { i32x8 v8; i32x4 v4[2]; } u;
      u.v4[0] = *(const i32x4*)(Bs8 + col*128 + SWZ(col, kbyte));
      u.v4[1] = *(const i32x4*)(Bs8 + col*128 + SWZ(col, kbyte+16));
      bfr[n] = u.v8;
    }
#pragma unroll
    for (int m=0;m<4;++m)
#pragma unroll
      for (int n=0;n<4;++n)
        acc[m][n] = mfma_f8(af[m], bfr[n], acc[m][n]);
  }

  float bv[4];
#pragma unroll
  for (int n=0;n<4;++n) bv[n] = bout[colbase + wn*64 + n*16 + (lane&15)];
#pragma unroll
  for (int m=0;m<4;++m)
#pragma unroll
    for (int n=0;n<4;++n)
#pragma unroll
      for (int r=0;r<4;++r) acc[m][n][r] += bv[n];
  float rm[4][4], rs[4][4];
#pragma unroll
  for (int m=0;m<4;++m)
#pragma unroll
    for (int r=0;r<4;++r){
      float mx = fmaxf(fmaxf(acc[m][0][r],acc[m][1][r]), fmaxf(acc[m][2][r],acc[m][3][r]));
      mx = fmaxf(mx, __shfl_xor(mx,1,16));
      mx = fmaxf(mx, __shfl_xor(mx,2,16));
      mx = fmaxf(mx, __shfl_xor(mx,4,16));
      mx = fmaxf(mx, __shfl_xor(mx,8,16));
      float sv = __expf(acc[m][0][r]-mx) + __expf(acc[m][1][r]-mx)
               + __expf(acc[m][2][r]-mx) + __expf(acc[m][3][r]-mx);
      sv += __shfl_xor(sv,1,16);
      sv += __shfl_xor(sv,2,16);
      sv += __shfl_xor(sv,4,16);
      sv += __shfl_xor(sv,8,16);
      rm[m][r]=mx; rs[m][r]=sv;
    }
  const int slice = vt*2 + wn;
  if ((lane&15)==0){
#pragma unroll
    for (int m=0;m<4;++m)
#pragma unroll
      for (int r=0;r<4;++r){
        const int rloc = wm*64 + m*16 + (lane>>4)*4 + r;
        partm[(size_t)slice*2048 + rowbase + rloc] = rm[m][r];
        parts[(size_t)slice*2048 + rowbase + rloc] = rs[m][r];
      }
  }
#pragma unroll
  for (int m=0;m<4;++m)
#pragma unroll
    for (int r=0;r<4;++r){
      const int rloc = wm*64 + m*16 + (lane>>4)*4 + r;
      const int gg = gts[rloc] - colbase - wn*64;
      if (gg >= 0 && gg < 64 && (gg&15)==(lane&15)){
        const int n = gg>>4;
        const float val = (n==0)?acc[m][0][r] : (n==1)?acc[m][1][r]
                        : (n==2)?acc[m][2][r] : acc[m][3][r];
        gtl[rowbase+rloc] = val;
      }
    }
}

// LSE finalize + mean fused.
__global__ __launch_bounds__(256) void lse_finalize2(
    const float* __restrict__ partm, const float* __restrict__ parts,
    const float* __restrict__ gtl, float* __restrict__ out)
{
  __shared__ float red[4];
  const int r = blockIdx.x*256 + threadIdx.x;
  float m = -1e30f;
  for (int i=0;i<NSLICE;++i) m = fmaxf(m, partm[(size_t)i*2048 + r]);
  float s = 0.f;
  for (int i=0;i<NSLICE;++i) s += parts[(size_t)i*2048 + r]*__expf(partm[(size_t)i*2048 + r]-m);
  float v = (m + logf(s) - gtl[r]) * (1.0f/2048.0f);
#pragma unroll
  for (int off=32;off>=1;off>>=1) v += __shfl_down(v, off, 64);
  if ((threadIdx.x&63)==0) red[threadIdx.x>>6]=v;
  __syncthreads();
  if (threadIdx.x==0) atomicAdd(out, red[0]+red[1]+red[2]+red[3]);
}

extern "C" void kernel_launch(void* const* d_in, const int* in_sizes, int n_in,
                              void* d_out, int out_size, void* d_ws, size_t ws_size,
                              hipStream_t stream)
{
  const int*   tok  = (const int*)d_in[0];
  const int*   gt   = (const int*)d_in[1];
  const float* emb  = (const float*)d_in[2];
  const float* Wih  = (const float*)d_in[3];
  const float* Whh  = (const float*)d_in[4];
  const float* bias = (const float*)d_in[5];
  const float* Wout = (const float*)d_in[6];
  const float* bout = (const float*)d_in[7];
  float* out = (float*)d_out;

  char* base = (char*)d_ws;
  u8*    WoutT8 = (u8*)base;            base += 32768000;   // 32000*1024*1
  u16*   WihT  = (u16*)base;            base += 8388608;
  u16*   WhhT  = (u16*)base;            base += 8388608;
  u16*   embg  = (u16*)base;            base += 4194304;
  float* xgP   = (float*)base;          base += 33554432;   // 2048*4096*4 (permuted)
  u8*    hsf8  = (u8*)base;             base += 2097152;    // 2048*1024*1
  float* cbuf  = (float*)base;          base += 131072;     // zbuf start
  u16*   hb0   = (u16*)base;            base += 65536;
  u16*   hb1   = (u16*)base;            base += 65536;
  unsigned* bar = (unsigned*)base;      base += 1024;       // 8 counters, 128B apart
  float* partm = (float*)base;          base += 4096000;
  float* parts = (float*)base;          base += 4096000;
  float* gtl   = (float*)base;          base += 8192;

  // prep: Wih/Whh transposes + emb gather + zero(c,h0,h1,bar) + zero out[0]
  prep_kernel<<<4353, 256, 0, stream>>>(Wih, Whh, tok, emb,
                                        WihT, WhhT, embg, cbuf, out);

  xproj_gemm<<<512, 256, 0, stream>>>(embg, WihT, bias, xgP);

  // Regular launch: 256 blocks on 256 CUs co-schedule trivially (4 waves,
  // 24.6KB LDS, ~130 VGPR); the custom barrier needs only co-residency.
  lstm_persistent<<<256, 256, 0, stream>>>(WhhT, xgP, hb0, hb1, hsf8, bar,
                                           Wout, WoutT8);

  logits_gemm_lse<<<4000, 256, 0, stream>>>(hsf8, WoutT8, bout, gt, partm, parts, gtl);
  lse_finalize2<<<8, 256, 0, stream>>>(partm, parts, gtl, out);
}